// Round 3
// baseline (704.167 us; speedup 1.0000x reference)
//
#include <hip/hip_runtime.h>
#include <cmath>

// ---------------------------------------------------------------------------
// EncoderLayer: x -> MHA -> +res -> LN1 -> FFN(GELU) -> +res -> LN2
// B=2 L=2048 D=1024 H=16 dk=64 F=4096  (M = B*L = 4096 rows)
// Internal compute: bf16 MFMA (16x16x32), fp32 accumulate, fp32 LN/residual.
// ---------------------------------------------------------------------------

typedef unsigned short u16;
typedef unsigned int u32;
typedef __attribute__((ext_vector_type(8))) __bf16 bf16x8;
typedef __attribute__((ext_vector_type(4))) float f32x4;

#define MFMA16(a, b, c) __builtin_amdgcn_mfma_f32_16x16x32_bf16(a, b, c, 0, 0, 0)

__device__ __forceinline__ u16 f2bf(float f) {
  u32 u = __builtin_bit_cast(u32, f);
  u += 0x7fffu + ((u >> 16) & 1u);   // round-to-nearest-even
  return (u16)(u >> 16);
}

__device__ __forceinline__ u32 pack2bf(float lo, float hi) {
  return (u32)f2bf(lo) | ((u32)f2bf(hi) << 16);
}

__device__ __forceinline__ bf16x8 ld_frag(const u16* p) {
  return __builtin_bit_cast(bf16x8, *(const uint4*)p);
}

__device__ __forceinline__ float fexp2(float x) {
#if __has_builtin(__builtin_amdgcn_exp2f)
  return __builtin_amdgcn_exp2f(x);
#else
  return exp2f(x);
#endif
}

// ---------------- fp32 -> bf16 elementwise convert (x) ----------------------
__global__ __launch_bounds__(256) void cvt_bf16_k(const float* __restrict__ src,
                                                  u16* __restrict__ dst) {
  int i = (blockIdx.x * 256 + threadIdx.x) * 4;
  float4 v = *(const float4*)(src + i);
  ushort4 o;
  o.x = f2bf(v.x); o.y = f2bf(v.y); o.z = f2bf(v.z); o.w = f2bf(v.w);
  *(ushort4*)(dst + i) = o;
}

// ---------------- fp32 [R][C] -> bf16 [C][R] transpose ----------------------
__global__ __launch_bounds__(256) void transpose_bf16_k(const float* __restrict__ src,
                                                        u16* __restrict__ dst,
                                                        int R, int C) {
  __shared__ float tile[32][33];
  int tx = threadIdx.x & 31, ty = threadIdx.x >> 5;  // 32 x 8
  int c0 = blockIdx.x * 32, r0 = blockIdx.y * 32;
#pragma unroll
  for (int i = 0; i < 4; i++)
    tile[ty + 8 * i][tx] = src[(long)(r0 + ty + 8 * i) * C + c0 + tx];
  __syncthreads();
#pragma unroll
  for (int i = 0; i < 4; i++)
    dst[(long)(c0 + ty + 8 * i) * R + r0 + tx] = f2bf(tile[tx][ty + 8 * i]);
}

// ---------------- GEMM: C[M][N] = A[M][K] * BT[N][K]^T ----------------------
// 64x64 block tile, 4 waves (each wave: 16 rows x 64 cols), BK=32.
// MODE 0: QKV epilogue (scatter to q [bh][L][dk] *0.125*log2e, k [bh][L][dk],
//         vT [bh][dk][L])
// MODE 1: fp32 out + bias
// MODE 2: bf16 out + bias + exact GELU
template <int MODE>
__global__ __launch_bounds__(256) void gemm_k(
    const u16* __restrict__ A, const u16* __restrict__ BT, int M, int N, int K,
    const float* __restrict__ bias, float* __restrict__ outF, u16* __restrict__ outB,
    u16* __restrict__ qd, u16* __restrict__ kd, u16* __restrict__ vTd,
    const float* __restrict__ bq, const float* __restrict__ bk, const float* __restrict__ bv) {
  __shared__ u16 As[64][40];  // +8 pad: <=2-way bank aliasing (free)
  __shared__ u16 Bs[64][40];
  const int tid = threadIdx.x;
  const int wave = tid >> 6, lane = tid & 63, quad = lane >> 4, l16 = lane & 15;
  const int m0 = blockIdx.y * 64, n0 = blockIdx.x * 64;
  const int srow = tid >> 2, sseg = (tid & 3) * 8;
  const u16* aSrc = A + (long)(m0 + srow) * K + sseg;
  const u16* bSrc = BT + (long)(n0 + srow) * K + sseg;

  f32x4 acc[4] = {};
  for (int k0 = 0; k0 < K; k0 += 32) {
    __syncthreads();
    *(uint4*)&As[srow][sseg] = *(const uint4*)(aSrc + k0);
    *(uint4*)&Bs[srow][sseg] = *(const uint4*)(bSrc + k0);
    __syncthreads();
    bf16x8 a = ld_frag(&As[wave * 16 + l16][quad * 8]);
#pragma unroll
    for (int nt = 0; nt < 4; nt++) {
      bf16x8 b = ld_frag(&Bs[nt * 16 + l16][quad * 8]);
      acc[nt] = MFMA16(a, b, acc[nt]);
    }
  }

  if (MODE == 0) {
#pragma unroll
    for (int nt = 0; nt < 4; nt++) {
      int n = n0 + nt * 16 + l16;
      int mat = n >> 10, nn = n & 1023, hh = nn >> 6, dd = nn & 63;
      const float* bp = (mat == 0) ? bq : ((mat == 1) ? bk : bv);
      float bb = bp[nn];
#pragma unroll
      for (int r = 0; r < 4; r++) {
        int m = m0 + wave * 16 + quad * 4 + r;
        int bI = m >> 11, ll = m & 2047;
        float v = acc[nt][r] + bb;
        if (mat == 0) {
          // fold 1/sqrt(dk) * log2(e) so attention can use exp2 directly
          qd[((long)((bI * 16 + hh) * 2048 + ll)) * 64 + dd] = f2bf(v * 0.18033688011112043f);
        } else if (mat == 1) {
          kd[((long)((bI * 16 + hh) * 2048 + ll)) * 64 + dd] = f2bf(v);
        } else {
          vTd[((long)((bI * 16 + hh) * 64 + dd)) * 2048 + ll] = f2bf(v);
        }
      }
    }
  } else if (MODE == 1) {
#pragma unroll
    for (int nt = 0; nt < 4; nt++) {
      int n = n0 + nt * 16 + l16;
      float bb = bias[n];
#pragma unroll
      for (int r = 0; r < 4; r++) {
        int m = m0 + wave * 16 + quad * 4 + r;
        outF[(long)m * N + n] = acc[nt][r] + bb;
      }
    }
  } else {
#pragma unroll
    for (int nt = 0; nt < 4; nt++) {
      int n = n0 + nt * 16 + l16;
      float bb = bias[n];
#pragma unroll
      for (int r = 0; r < 4; r++) {
        int m = m0 + wave * 16 + quad * 4 + r;
        float v = acc[nt][r] + bb;
        v = 0.5f * v * (1.0f + erff(v * 0.70710678118654752f));  // exact GELU
        outB[(long)m * N + n] = f2bf(v);
      }
    }
  }
}

// ---------------- flash attention (transposed S^T layout) -------------------
// grid (L/64, B*H), 4 waves/block, wave owns 16 q rows; 64-key chunks.
// S^T = K * Q^T via MFMA(A=K frag, B=Q^T frag): lane holds
//   S^T[key = f*16 + quad*4 + r][q = l16].
// Softmax per q = cross-quad reduction: __shfl_xor 16, 32 only.
// O^T = V^T * P^T: A = V^T frag (from vT buffer), B = P^T frag via a
// per-wave LDS bounce ([q][key] layout) with NO barriers (wave-internal
// s_waitcnt lgkmcnt(0) instead).
// q is pre-scaled by 0.125*log2(e) so p = exp2(s - m).
__global__ __launch_bounds__(256) void attn_k(const u16* __restrict__ qd,
                                              const u16* __restrict__ kd,
                                              const u16* __restrict__ vTd,
                                              u16* __restrict__ ctx) {
  const int tid = threadIdx.x;
  const int wave = tid >> 6, lane = tid & 63, quad = lane >> 4, l16 = lane & 15;
  const int bh = blockIdx.y;
  const u16* Q = qd + (long)bh * 2048 * 64;
  const u16* Kp = kd + (long)bh * 2048 * 64;
  const u16* Vt = vTd + (long)bh * 64 * 2048;
  const int qbase = blockIdx.x * 64 + wave * 16;

  // Q as B operand: lane holds Q[q=l16][d = quad*8+j], two dk halves
  bf16x8 qf0 = ld_frag(Q + (qbase + l16) * 64 + quad * 8);
  bf16x8 qf1 = ld_frag(Q + (qbase + l16) * 64 + 32 + quad * 8);

  f32x4 o[4] = {};            // O^T[d = nt*16+quad*4+r][q = l16]
  float m = -1e30f, l = 0.f;  // per q (= per l16), replicated across quads

  __shared__ __align__(16) u16 P[4][16][72];  // [wave][q][key] (+pad, 16B rows)
  u16* prow = &P[wave][l16][0];

  const u16* kbase = Kp + l16 * 64 + quad * 8;    // + j0*64 + f*1024 + dh*32
  const u16* vbase = Vt + l16 * 2048 + quad * 8;  // + nt*32768 + j0 + kh*32

#pragma unroll 1
  for (int j0 = 0; j0 < 2048; j0 += 64) {
    // ---- S^T = K Q^T over 64 keys (4 key tiles x 2 dk halves) ----
    const u16* kp = kbase + j0 * 64;
    f32x4 st[4];
#pragma unroll
    for (int f = 0; f < 4; f++) {
      bf16x8 k0 = ld_frag(kp + f * 1024);
      bf16x8 k1 = ld_frag(kp + f * 1024 + 32);
      f32x4 s = {};
      s = MFMA16(k0, qf0, s);
      s = MFMA16(k1, qf1, s);
      st[f] = s;
    }

    // ---- V^T A-fragments for this chunk (issue early, consumed later) ----
    bf16x8 vf[4][2];
#pragma unroll
    for (int nt = 0; nt < 4; nt++) {
      vf[nt][0] = ld_frag(vbase + nt * 32768 + j0);
      vf[nt][1] = ld_frag(vbase + nt * 32768 + j0 + 32);
    }

    // ---- online softmax over the 64-key chunk ----
    float mx = -1e30f;
#pragma unroll
    for (int f = 0; f < 4; f++) {
      mx = fmaxf(mx, fmaxf(fmaxf(st[f][0], st[f][1]), fmaxf(st[f][2], st[f][3])));
    }
    mx = fmaxf(mx, __shfl_xor(mx, 16));
    mx = fmaxf(mx, __shfl_xor(mx, 32));
    float mn = fmaxf(m, mx);
    float al = fexp2(m - mn);
    float p[4][4];
    float sm = 0.f;
#pragma unroll
    for (int f = 0; f < 4; f++) {
#pragma unroll
      for (int r = 0; r < 4; r++) {
        p[f][r] = fexp2(st[f][r] - mn);
        sm += p[f][r];
      }
    }
    sm += __shfl_xor(sm, 16);
    sm += __shfl_xor(sm, 32);
    l = l * al + sm;
    m = mn;
#pragma unroll
    for (int nt = 0; nt < 4; nt++) {
      o[nt][0] *= al; o[nt][1] *= al; o[nt][2] *= al; o[nt][3] *= al;
    }

    // ---- pack P^T to bf16, per-wave LDS bounce [q][key] ----
#pragma unroll
    for (int f = 0; f < 4; f++) {
      uint2 u;
      u.x = pack2bf(p[f][0], p[f][1]);
      u.y = pack2bf(p[f][2], p[f][3]);
      *(uint2*)(prow + f * 16 + quad * 4) = u;
    }
    // wave-internal write->read ordering (no inter-wave dep, no barrier)
    __asm__ volatile("s_waitcnt lgkmcnt(0)" ::: "memory");

    // ---- O^T += V^T P^T ----
#pragma unroll
    for (int kh = 0; kh < 2; kh++) {
      bf16x8 pf = ld_frag(prow + kh * 32 + quad * 8);
#pragma unroll
      for (int nt = 0; nt < 4; nt++) {
        o[nt] = MFMA16(vf[nt][kh], pf, o[nt]);
      }
    }
  }

  // ---- epilogue: divide by l, write ctx[b][l][h*64+d] ----
  const int bI = bh >> 4, hh = bh & 15;
  const float rl = 1.0f / l;
  const long row = (long)(bI * 2048 + qbase + l16);
#pragma unroll
  for (int nt = 0; nt < 4; nt++) {
    ushort4 w;
    w.x = f2bf(o[nt][0] * rl);
    w.y = f2bf(o[nt][1] * rl);
    w.z = f2bf(o[nt][2] * rl);
    w.w = f2bf(o[nt][3] * rl);
    *(ushort4*)(ctx + row * 1024 + hh * 64 + nt * 16 + quad * 4) = w;
  }
}

// ---------------- residual + LayerNorm -------------------------------------
// out = LN(a+b)*g + be ; optional bf16 copy of out
__global__ __launch_bounds__(256) void ln_k(const float* __restrict__ a,
                                            const float* __restrict__ b,
                                            const float* __restrict__ g,
                                            const float* __restrict__ be,
                                            float* __restrict__ outF,
                                            u16* __restrict__ outB) {
  const int row = blockIdx.x, tid = threadIdx.x;
  const float* pa = a + (long)row * 1024;
  const float* pb = b + (long)row * 1024;
  float v[4], s = 0.f, sq = 0.f;
#pragma unroll
  for (int i = 0; i < 4; i++) {
    int c = i * 256 + tid;
    v[i] = pa[c] + pb[c];
    s += v[i];
    sq += v[i] * v[i];
  }
#pragma unroll
  for (int off = 1; off < 64; off <<= 1) {
    s += __shfl_xor(s, off);
    sq += __shfl_xor(sq, off);
  }
  __shared__ float red[10];
  int wave = tid >> 6, lane = tid & 63;
  if (lane == 0) { red[wave * 2] = s; red[wave * 2 + 1] = sq; }
  __syncthreads();
  if (tid == 0) {
    float S = red[0] + red[2] + red[4] + red[6];
    float Q = red[1] + red[3] + red[5] + red[7];
    float mu = S * (1.0f / 1024.0f);
    float var = Q * (1.0f / 1024.0f) - mu * mu;
    red[8] = mu;
    red[9] = rsqrtf(var + 1e-5f);
  }
  __syncthreads();
  float mu = red[8], rstd = red[9];
#pragma unroll
  for (int i = 0; i < 4; i++) {
    int c = i * 256 + tid;
    float o = (v[i] - mu) * rstd * g[c] + be[c];
    outF[(long)row * 1024 + c] = o;
    if (outB) outB[(long)row * 1024 + c] = f2bf(o);
  }
}

// ---------------------------------------------------------------------------
extern "C" void kernel_launch(void* const* d_in, const int* in_sizes, int n_in,
                              void* d_out, int out_size, void* d_ws, size_t ws_size,
                              hipStream_t stream) {
  const float* x  = (const float*)d_in[0];
  const float* Wq = (const float*)d_in[1];  const float* bq = (const float*)d_in[2];
  const float* Wk = (const float*)d_in[3];  const float* bk = (const float*)d_in[4];
  const float* Wv = (const float*)d_in[5];  const float* bv = (const float*)d_in[6];
  const float* Wo = (const float*)d_in[7];  const float* bo = (const float*)d_in[8];
  const float* W1 = (const float*)d_in[9];  const float* b1 = (const float*)d_in[10];
  const float* W2 = (const float*)d_in[11]; const float* b2 = (const float*)d_in[12];
  const float* g1 = (const float*)d_in[13]; const float* be1 = (const float*)d_in[14];
  const float* g2 = (const float*)d_in[15]; const float* be2 = (const float*)d_in[16];

  char* ws = (char*)d_ws;
  size_t off = 0;
  auto alloc = [&](size_t bytes) {
    size_t o = off;
    off += (bytes + 255) & ~(size_t)255;
    return o;
  };
  u16*   xb     = (u16*)(ws + alloc(4096UL * 1024 * 2));
  u16*   wqkvT  = (u16*)(ws + alloc(3072UL * 1024 * 2));
  u16*   woT    = (u16*)(ws + alloc(1024UL * 1024 * 2));
  u16*   w1T    = (u16*)(ws + alloc(4096UL * 1024 * 2));
  u16*   w2T    = (u16*)(ws + alloc(1024UL * 4096 * 2));
  u16*   qb     = (u16*)(ws + alloc(32UL * 2048 * 64 * 2));
  u16*   kb     = (u16*)(ws + alloc(32UL * 2048 * 64 * 2));
  u16*   vTb    = (u16*)(ws + alloc(32UL * 64 * 2048 * 2));
  u16*   ctx    = (u16*)(ws + alloc(4096UL * 1024 * 2));
  float* attnO  = (float*)(ws + alloc(4096UL * 1024 * 4));
  float* h      = (float*)(ws + alloc(4096UL * 1024 * 4));
  u16*   hb     = (u16*)(ws + alloc(4096UL * 1024 * 2));
  u16*   ff1    = (u16*)(ws + alloc(4096UL * 4096 * 2));
  float* ff2    = (float*)(ws + alloc(4096UL * 1024 * 4));
  if (off > ws_size) return;  // workspace too small: bail (bench will flag)

  // 1) bf16 conversions / weight transposes
  cvt_bf16_k<<<4096, 256, 0, stream>>>(x, xb);
  transpose_bf16_k<<<dim3(32, 32), 256, 0, stream>>>(Wq, wqkvT, 1024, 1024);
  transpose_bf16_k<<<dim3(32, 32), 256, 0, stream>>>(Wk, wqkvT + 1024 * 1024, 1024, 1024);
  transpose_bf16_k<<<dim3(32, 32), 256, 0, stream>>>(Wv, wqkvT + 2 * 1024 * 1024, 1024, 1024);
  transpose_bf16_k<<<dim3(32, 32), 256, 0, stream>>>(Wo, woT, 1024, 1024);
  transpose_bf16_k<<<dim3(128, 32), 256, 0, stream>>>(W1, w1T, 1024, 4096);
  transpose_bf16_k<<<dim3(32, 128), 256, 0, stream>>>(W2, w2T, 4096, 1024);

  // 2) QKV projection (N=3072 fused), scatter epilogue
  gemm_k<0><<<dim3(48, 64), 256, 0, stream>>>(xb, wqkvT, 4096, 3072, 1024,
                                              nullptr, nullptr, nullptr,
                                              qb, kb, vTb, bq, bk, bv);
  // 3) attention
  attn_k<<<dim3(32, 32), 256, 0, stream>>>(qb, kb, vTb, ctx);
  // 4) output projection
  gemm_k<1><<<dim3(16, 64), 256, 0, stream>>>(ctx, woT, 4096, 1024, 1024,
                                              bo, attnO, nullptr,
                                              nullptr, nullptr, nullptr, nullptr, nullptr, nullptr);
  // 5) residual + LN1 (fp32 h + bf16 hb)
  ln_k<<<4096, 256, 0, stream>>>(x, attnO, g1, be1, h, hb);
  // 6) FFN up + GELU
  gemm_k<2><<<dim3(64, 64), 256, 0, stream>>>(hb, w1T, 4096, 4096, 1024,
                                              b1, nullptr, ff1,
                                              nullptr, nullptr, nullptr, nullptr, nullptr, nullptr);
  // 7) FFN down
  gemm_k<1><<<dim3(16, 64), 256, 0, stream>>>(ff1, w2T, 4096, 1024, 4096,
                                              b2, ff2, nullptr,
                                              nullptr, nullptr, nullptr, nullptr, nullptr, nullptr);
  // 8) residual + LN2 -> out
  ln_k<<<4096, 256, 0, stream>>>(h, ff2, g2, be2, (float*)d_out, nullptr);
}

// Round 4
// 488.861 us; speedup vs baseline: 1.4404x; 1.4404x over previous
//
#include <hip/hip_runtime.h>
#include <cmath>

// ---------------------------------------------------------------------------
// EncoderLayer: x -> MHA -> +res -> LN1 -> FFN(GELU) -> +res -> LN2
// B=2 L=2048 D=1024 H=16 dk=64 F=4096  (M = B*L = 4096 rows)
// bf16 MFMA 16x16x32, fp32 accumulate, fp32 LN/residual.
// GEMM: m97-style 128x128 tile + global_load_lds(16B) + XOR-swizzled LDS.
// Attention: S^T flash with LDS-staged double-buffered K/V tiles.
// ---------------------------------------------------------------------------

typedef unsigned short u16;
typedef unsigned int u32;
typedef __attribute__((ext_vector_type(8))) __bf16 bf16x8;
typedef __attribute__((ext_vector_type(4))) float f32x4;

#define MFMA16(a, b, c) __builtin_amdgcn_mfma_f32_16x16x32_bf16(a, b, c, 0, 0, 0)

__device__ __forceinline__ u16 f2bf(float f) {
  u32 u = __builtin_bit_cast(u32, f);
  u += 0x7fffu + ((u >> 16) & 1u);   // round-to-nearest-even
  return (u16)(u >> 16);
}

__device__ __forceinline__ u32 pack2bf(float lo, float hi) {
  return (u32)f2bf(lo) | ((u32)f2bf(hi) << 16);
}

__device__ __forceinline__ bf16x8 ld_frag(const u16* p) {
  return __builtin_bit_cast(bf16x8, *(const uint4*)p);
}

__device__ __forceinline__ float fexp2(float x) {
#if __has_builtin(__builtin_amdgcn_exp2f)
  return __builtin_amdgcn_exp2f(x);
#else
  return exp2f(x);
#endif
}

// async global->LDS, 16B per lane; LDS dest = wave-uniform base + lane*16
__device__ __forceinline__ void gload16(const u16* g, u16* l) {
  __builtin_amdgcn_global_load_lds(
      (const __attribute__((address_space(1))) void*)g,
      (__attribute__((address_space(3))) void*)l, 16, 0, 0);
}

// ---------------- fp32 -> bf16 elementwise convert (x) ----------------------
__global__ __launch_bounds__(256) void cvt_bf16_k(const float* __restrict__ src,
                                                  u16* __restrict__ dst) {
  int i = (blockIdx.x * 256 + threadIdx.x) * 4;
  float4 v = *(const float4*)(src + i);
  ushort4 o;
  o.x = f2bf(v.x); o.y = f2bf(v.y); o.z = f2bf(v.z); o.w = f2bf(v.w);
  *(ushort4*)(dst + i) = o;
}

// ---------------- fp32 [R][C] -> bf16 [C][R] transpose ----------------------
__global__ __launch_bounds__(256) void transpose_bf16_k(const float* __restrict__ src,
                                                        u16* __restrict__ dst,
                                                        int R, int C) {
  __shared__ float tile[32][33];
  int tx = threadIdx.x & 31, ty = threadIdx.x >> 5;  // 32 x 8
  int c0 = blockIdx.x * 32, r0 = blockIdx.y * 32;
#pragma unroll
  for (int i = 0; i < 4; i++)
    tile[ty + 8 * i][tx] = src[(long)(r0 + ty + 8 * i) * C + c0 + tx];
  __syncthreads();
#pragma unroll
  for (int i = 0; i < 4; i++)
    dst[(long)(c0 + ty + 8 * i) * R + r0 + tx] = f2bf(tile[tx][ty + 8 * i]);
}

// ---------------- GEMM: C[M][N] = A[M][K] * BT[N][K]^T ----------------------
// 128x128 block tile, BK=32, 4 waves in 2x2; each wave 64x64 (4x4 MFMA tiles).
// LDS tiles unpadded [row][32k] (64B rows), segs XOR-swizzled: LDS[r][s] holds
// global seg s^(r&3). global_load_lds 16B, 4 issues/wave/chunk.
// MODE 0: QKV scatter epilogue; MODE 1: fp32+bias; MODE 2: bf16+bias+GELU.
template <int MODE>
__global__ __launch_bounds__(256) void gemm_k(
    const u16* __restrict__ A, const u16* __restrict__ BT, int M, int N, int K,
    const float* __restrict__ bias, float* __restrict__ outF, u16* __restrict__ outB,
    u16* __restrict__ qd, u16* __restrict__ kd, u16* __restrict__ vTd,
    const float* __restrict__ bq, const float* __restrict__ bk, const float* __restrict__ bv) {
  __shared__ u16 As[128 * 32];
  __shared__ u16 Bs[128 * 32];
  const int tid = threadIdx.x;
  const int wave = tid >> 6, lane = tid & 63, quad = lane >> 4, l16 = lane & 15;
  const int wm = wave >> 1, wn = wave & 1;
  const int m0 = blockIdx.y * 128, n0 = blockIdx.x * 128;

  // staging: issue i covers rows wave*32 + i*16 + lane/4; seg lane&3 (16B units)
  const int srow = lane >> 2;                  // 0..15
  const int sxor = (lane & 3) ^ (srow & 3);    // swizzled source seg
  const u16* aS0 = A + (long)(m0 + wave * 32 + srow) * K + sxor * 8;
  const u16* aS1 = A + (long)(m0 + wave * 32 + 16 + srow) * K + sxor * 8;
  const u16* bS0 = BT + (long)(n0 + wave * 32 + srow) * K + sxor * 8;
  const u16* bS1 = BT + (long)(n0 + wave * 32 + 16 + srow) * K + sxor * 8;
  u16* aL0 = &As[(wave * 2 + 0) * 512];
  u16* aL1 = &As[(wave * 2 + 1) * 512];
  u16* bL0 = &Bs[(wave * 2 + 0) * 512];
  u16* bL1 = &Bs[(wave * 2 + 1) * 512];

  // fragment read offsets (u16 units): row*32 + (quad^(row&3))*8
  int aoff[4], boff[4];
#pragma unroll
  for (int t = 0; t < 4; t++) {
    int ra = wm * 64 + t * 16 + l16;
    aoff[t] = ra * 32 + ((quad ^ (l16 & 3)) * 8);
    int rb = wn * 64 + t * 16 + l16;
    boff[t] = rb * 32 + ((quad ^ (l16 & 3)) * 8);
  }

  f32x4 acc[4][4] = {};

  for (int k0 = 0; k0 < K; k0 += 32) {
    __syncthreads();
    gload16(aS0 + k0, aL0);
    gload16(aS1 + k0, aL1);
    gload16(bS0 + k0, bL0);
    gload16(bS1 + k0, bL1);
    __syncthreads();   // compiler drains vmcnt before s_barrier
    bf16x8 af[4], bfr[4];
#pragma unroll
    for (int t = 0; t < 4; t++) af[t] = ld_frag(&As[aoff[t]]);
#pragma unroll
    for (int t = 0; t < 4; t++) bfr[t] = ld_frag(&Bs[boff[t]]);
#pragma unroll
    for (int mt = 0; mt < 4; mt++)
#pragma unroll
      for (int nt = 0; nt < 4; nt++)
        acc[mt][nt] = MFMA16(af[mt], bfr[nt], acc[mt][nt]);
  }

  if (MODE == 0) {
#pragma unroll
    for (int nt = 0; nt < 4; nt++) {
      int n = n0 + wn * 64 + nt * 16 + l16;
      int mat = n >> 10, nn = n & 1023, hh = nn >> 6, dd = nn & 63;
      const float* bp = (mat == 0) ? bq : ((mat == 1) ? bk : bv);
      float bb = bp[nn];
#pragma unroll
      for (int mt = 0; mt < 4; mt++) {
#pragma unroll
        for (int r = 0; r < 4; r++) {
          int mr = m0 + wm * 64 + mt * 16 + quad * 4 + r;
          int bI = mr >> 11, ll = mr & 2047;
          float v = acc[mt][nt][r] + bb;
          if (mat == 0) {
            // fold 1/sqrt(dk)*log2(e) so attention uses exp2 directly
            qd[((long)((bI * 16 + hh) * 2048 + ll)) * 64 + dd] = f2bf(v * 0.18033688011112043f);
          } else if (mat == 1) {
            kd[((long)((bI * 16 + hh) * 2048 + ll)) * 64 + dd] = f2bf(v);
          } else {
            vTd[((long)((bI * 16 + hh) * 64 + dd)) * 2048 + ll] = f2bf(v);
          }
        }
      }
    }
  } else if (MODE == 1) {
#pragma unroll
    for (int nt = 0; nt < 4; nt++) {
      int n = n0 + wn * 64 + nt * 16 + l16;
      float bb = bias[n];
#pragma unroll
      for (int mt = 0; mt < 4; mt++) {
#pragma unroll
        for (int r = 0; r < 4; r++) {
          int mr = m0 + wm * 64 + mt * 16 + quad * 4 + r;
          outF[(long)mr * N + n] = acc[mt][nt][r] + bb;
        }
      }
    }
  } else {
#pragma unroll
    for (int nt = 0; nt < 4; nt++) {
      int n = n0 + wn * 64 + nt * 16 + l16;
      float bb = bias[n];
#pragma unroll
      for (int mt = 0; mt < 4; mt++) {
#pragma unroll
        for (int r = 0; r < 4; r++) {
          int mr = m0 + wm * 64 + mt * 16 + quad * 4 + r;
          float v = acc[mt][nt][r] + bb;
          v = 0.5f * v * (1.0f + erff(v * 0.70710678118654752f));  // exact GELU
          outB[(long)mr * N + n] = f2bf(v);
        }
      }
    }
  }
}

// ---------------- flash attention (S^T, LDS-staged K/V) ---------------------
// grid (L/64, B*H), 4 waves; wave owns 16 q rows; 64-key chunks.
// K tile [64 key][64 dk], V tile [64 dk][64 key] (from vT), both 8KB bf16,
// XOR-swizzled segs (s^(row&7)), double-buffered, staged via global_load_lds.
// One __syncthreads per chunk; prefetch of chunk j+1 stays in flight across
// the softmax/PV body. q pre-scaled by 0.125*log2(e) -> p = exp2(s-m).
__global__ __launch_bounds__(256) void attn_k(const u16* __restrict__ qd,
                                              const u16* __restrict__ kd,
                                              const u16* __restrict__ vTd,
                                              u16* __restrict__ ctx) {
  __shared__ u16 Ks[2][64 * 64];
  __shared__ u16 Vs[2][64 * 64];
  __shared__ __align__(16) u16 P[4][16][72];  // per-wave P^T bounce
  const int tid = threadIdx.x;
  const int wave = tid >> 6, lane = tid & 63, quad = lane >> 4, l16 = lane & 15;
  const int bh = blockIdx.y;
  const u16* Q = qd + (long)bh * 2048 * 64;
  const u16* Kp = kd + (long)bh * 2048 * 64;
  const u16* Vt = vTd + (long)bh * 64 * 2048;
  const int qbase = blockIdx.x * 64 + wave * 16;

  // Q as B operand: lane holds Q[q=l16][d = quad*8+j], two dk halves
  bf16x8 qf0 = ld_frag(Q + (qbase + l16) * 64 + quad * 8);
  bf16x8 qf1 = ld_frag(Q + (qbase + l16) * 64 + 32 + quad * 8);

  f32x4 o[4] = {};            // O^T[d = nt*16+quad*4+r][q = l16]
  float m = -1e30f, l = 0.f;  // per q (= per l16), replicated across quads
  u16* prow = &P[wave][l16][0];

  // staging: issue i covers 8 rows (128B each): r = wave*16 + i*8 + lane/8
  const int srow = lane >> 3;                // 0..7
  const int sx = (lane & 7) ^ srow;          // swizzled source seg (16B units)
  const int kr0 = wave * 16 + srow;
  const int kr1 = wave * 16 + 8 + srow;

  // fragment seg offsets (u16 units): (g ^ (l16&7))*8
  const int fs0 = ((0 * 4 + quad) ^ (l16 & 7)) * 8;  // K dh=0
  const int fs1 = ((1 * 4 + quad) ^ (l16 & 7)) * 8;  // K dh=1
  const int vs0 = fs0;                               // V kh=0 (same formula)
  const int vs1 = fs1;                               // V kh=1

  auto stage = [&](int buf, int j0) {
    gload16(Kp + (long)(j0 + kr0) * 64 + sx * 8, &Ks[buf][(wave * 2 + 0) * 512]);
    gload16(Kp + (long)(j0 + kr1) * 64 + sx * 8, &Ks[buf][(wave * 2 + 1) * 512]);
    gload16(Vt + (long)kr0 * 2048 + j0 + sx * 8, &Vs[buf][(wave * 2 + 0) * 512]);
    gload16(Vt + (long)kr1 * 2048 + j0 + sx * 8, &Vs[buf][(wave * 2 + 1) * 512]);
  };

  stage(0, 0);

#pragma unroll 1
  for (int j0 = 0; j0 < 2048; j0 += 64) {
    const int buf = (j0 >> 6) & 1;
    __syncthreads();                       // staged chunk visible; prev body done
    if (j0 + 64 < 2048) stage(buf ^ 1, j0 + 64);

    // ---- S^T = K Q^T over 64 keys ----
    const u16* kb = &Ks[buf][0];
    f32x4 st[4];
#pragma unroll
    for (int f = 0; f < 4; f++) {
      bf16x8 k0 = ld_frag(kb + (f * 16 + l16) * 64 + fs0);
      bf16x8 k1 = ld_frag(kb + (f * 16 + l16) * 64 + fs1);
      f32x4 s = {};
      s = MFMA16(k0, qf0, s);
      s = MFMA16(k1, qf1, s);
      st[f] = s;
    }

    // ---- online softmax over the 64-key chunk (cross-quad reduce) ----
    float mx = -1e30f;
#pragma unroll
    for (int f = 0; f < 4; f++)
      mx = fmaxf(mx, fmaxf(fmaxf(st[f][0], st[f][1]), fmaxf(st[f][2], st[f][3])));
    mx = fmaxf(mx, __shfl_xor(mx, 16));
    mx = fmaxf(mx, __shfl_xor(mx, 32));
    float mn = fmaxf(m, mx);
    float al = fexp2(m - mn);
    float p[4][4];
    float sm = 0.f;
#pragma unroll
    for (int f = 0; f < 4; f++) {
#pragma unroll
      for (int r = 0; r < 4; r++) {
        p[f][r] = fexp2(st[f][r] - mn);
        sm += p[f][r];
      }
    }
    sm += __shfl_xor(sm, 16);
    sm += __shfl_xor(sm, 32);
    l = l * al + sm;
    m = mn;
#pragma unroll
    for (int nt = 0; nt < 4; nt++) {
      o[nt][0] *= al; o[nt][1] *= al; o[nt][2] *= al; o[nt][3] *= al;
    }

    // ---- pack P^T to bf16, per-wave LDS bounce [q][key] ----
#pragma unroll
    for (int f = 0; f < 4; f++) {
      uint2 u;
      u.x = pack2bf(p[f][0], p[f][1]);
      u.y = pack2bf(p[f][2], p[f][3]);
      *(uint2*)(prow + f * 16 + quad * 4) = u;
    }
    // wave-internal write->read ordering (no inter-wave dep, no barrier)
    __asm__ volatile("s_waitcnt lgkmcnt(0)" ::: "memory");

    // ---- O^T += V^T P^T ----
    const u16* vb = &Vs[buf][0];
#pragma unroll
    for (int kh = 0; kh < 2; kh++) {
      bf16x8 pf = ld_frag(prow + kh * 32 + quad * 8);
      const int vss = kh ? vs1 : vs0;
#pragma unroll
      for (int nt = 0; nt < 4; nt++) {
        o[nt] = MFMA16(ld_frag(vb + (nt * 16 + l16) * 64 + vss), pf, o[nt]);
      }
    }
  }

  // ---- epilogue: divide by l, write ctx[b][l][h*64+d] ----
  const int bI = bh >> 4, hh = bh & 15;
  const float rl = 1.0f / l;
  const long row = (long)(bI * 2048 + qbase + l16);
#pragma unroll
  for (int nt = 0; nt < 4; nt++) {
    ushort4 w;
    w.x = f2bf(o[nt][0] * rl);
    w.y = f2bf(o[nt][1] * rl);
    w.z = f2bf(o[nt][2] * rl);
    w.w = f2bf(o[nt][3] * rl);
    *(ushort4*)(ctx + row * 1024 + hh * 64 + nt * 16 + quad * 4) = w;
  }
}

// ---------------- residual + LayerNorm -------------------------------------
__global__ __launch_bounds__(256) void ln_k(const float* __restrict__ a,
                                            const float* __restrict__ b,
                                            const float* __restrict__ g,
                                            const float* __restrict__ be,
                                            float* __restrict__ outF,
                                            u16* __restrict__ outB) {
  const int row = blockIdx.x, tid = threadIdx.x;
  const float* pa = a + (long)row * 1024;
  const float* pb = b + (long)row * 1024;
  float v[4], s = 0.f, sq = 0.f;
#pragma unroll
  for (int i = 0; i < 4; i++) {
    int c = i * 256 + tid;
    v[i] = pa[c] + pb[c];
    s += v[i];
    sq += v[i] * v[i];
  }
#pragma unroll
  for (int off = 1; off < 64; off <<= 1) {
    s += __shfl_xor(s, off);
    sq += __shfl_xor(sq, off);
  }
  __shared__ float red[10];
  int wave = tid >> 6, lane = tid & 63;
  if (lane == 0) { red[wave * 2] = s; red[wave * 2 + 1] = sq; }
  __syncthreads();
  if (tid == 0) {
    float S = red[0] + red[2] + red[4] + red[6];
    float Q = red[1] + red[3] + red[5] + red[7];
    float mu = S * (1.0f / 1024.0f);
    float var = Q * (1.0f / 1024.0f) - mu * mu;
    red[8] = mu;
    red[9] = rsqrtf(var + 1e-5f);
  }
  __syncthreads();
  float mu = red[8], rstd = red[9];
#pragma unroll
  for (int i = 0; i < 4; i++) {
    int c = i * 256 + tid;
    float o = (v[i] - mu) * rstd * g[c] + be[c];
    outF[(long)row * 1024 + c] = o;
    if (outB) outB[(long)row * 1024 + c] = f2bf(o);
  }
}

// ---------------------------------------------------------------------------
extern "C" void kernel_launch(void* const* d_in, const int* in_sizes, int n_in,
                              void* d_out, int out_size, void* d_ws, size_t ws_size,
                              hipStream_t stream) {
  const float* x  = (const float*)d_in[0];
  const float* Wq = (const float*)d_in[1];  const float* bq = (const float*)d_in[2];
  const float* Wk = (const float*)d_in[3];  const float* bk = (const float*)d_in[4];
  const float* Wv = (const float*)d_in[5];  const float* bv = (const float*)d_in[6];
  const float* Wo = (const float*)d_in[7];  const float* bo = (const float*)d_in[8];
  const float* W1 = (const float*)d_in[9];  const float* b1 = (const float*)d_in[10];
  const float* W2 = (const float*)d_in[11]; const float* b2 = (const float*)d_in[12];
  const float* g1 = (const float*)d_in[13]; const float* be1 = (const float*)d_in[14];
  const float* g2 = (const float*)d_in[15]; const float* be2 = (const float*)d_in[16];

  char* ws = (char*)d_ws;
  size_t off = 0;
  auto alloc = [&](size_t bytes) {
    size_t o = off;
    off += (bytes + 255) & ~(size_t)255;
    return o;
  };
  u16*   xb     = (u16*)(ws + alloc(4096UL * 1024 * 2));
  u16*   wqkvT  = (u16*)(ws + alloc(3072UL * 1024 * 2));
  u16*   woT    = (u16*)(ws + alloc(1024UL * 1024 * 2));
  u16*   w1T    = (u16*)(ws + alloc(4096UL * 1024 * 2));
  u16*   w2T    = (u16*)(ws + alloc(1024UL * 4096 * 2));
  u16*   qb     = (u16*)(ws + alloc(32UL * 2048 * 64 * 2));
  u16*   kb     = (u16*)(ws + alloc(32UL * 2048 * 64 * 2));
  u16*   vTb    = (u16*)(ws + alloc(32UL * 64 * 2048 * 2));
  u16*   ctx    = (u16*)(ws + alloc(4096UL * 1024 * 2));
  float* attnO  = (float*)(ws + alloc(4096UL * 1024 * 4));
  float* h      = (float*)(ws + alloc(4096UL * 1024 * 4));
  u16*   hb     = (u16*)(ws + alloc(4096UL * 1024 * 2));
  u16*   ff1    = (u16*)(ws + alloc(4096UL * 4096 * 2));
  float* ff2    = (float*)(ws + alloc(4096UL * 1024 * 4));
  if (off > ws_size) return;  // workspace too small: bail (bench will flag)

  // 1) bf16 conversions / weight transposes
  cvt_bf16_k<<<4096, 256, 0, stream>>>(x, xb);
  transpose_bf16_k<<<dim3(32, 32), 256, 0, stream>>>(Wq, wqkvT, 1024, 1024);
  transpose_bf16_k<<<dim3(32, 32), 256, 0, stream>>>(Wk, wqkvT + 1024 * 1024, 1024, 1024);
  transpose_bf16_k<<<dim3(32, 32), 256, 0, stream>>>(Wv, wqkvT + 2 * 1024 * 1024, 1024, 1024);
  transpose_bf16_k<<<dim3(32, 32), 256, 0, stream>>>(Wo, woT, 1024, 1024);
  transpose_bf16_k<<<dim3(128, 32), 256, 0, stream>>>(W1, w1T, 1024, 4096);
  transpose_bf16_k<<<dim3(32, 128), 256, 0, stream>>>(W2, w2T, 4096, 1024);

  // 2) QKV projection (N=3072 fused), scatter epilogue
  gemm_k<0><<<dim3(24, 32), 256, 0, stream>>>(xb, wqkvT, 4096, 3072, 1024,
                                              nullptr, nullptr, nullptr,
                                              qb, kb, vTb, bq, bk, bv);
  // 3) attention
  attn_k<<<dim3(32, 32), 256, 0, stream>>>(qb, kb, vTb, ctx);
  // 4) output projection
  gemm_k<1><<<dim3(8, 32), 256, 0, stream>>>(ctx, woT, 4096, 1024, 1024,
                                             bo, attnO, nullptr,
                                             nullptr, nullptr, nullptr, nullptr, nullptr, nullptr);
  // 5) residual + LN1 (fp32 h + bf16 hb)
  ln_k<<<4096, 256, 0, stream>>>(x, attnO, g1, be1, h, hb);
  // 6) FFN up + GELU
  gemm_k<2><<<dim3(32, 32), 256, 0, stream>>>(hb, w1T, 4096, 4096, 1024,
                                              b1, nullptr, ff1,
                                              nullptr, nullptr, nullptr, nullptr, nullptr, nullptr);
  // 7) FFN down
  gemm_k<1><<<dim3(8, 32), 256, 0, stream>>>(ff1, w2T, 4096, 1024, 4096,
                                             b2, ff2, nullptr,
                                             nullptr, nullptr, nullptr, nullptr, nullptr, nullptr);
  // 8) residual + LN2 -> out
  ln_k<<<4096, 256, 0, stream>>>(h, ff2, g2, be2, (float*)d_out, nullptr);
}

// Round 5
// 449.994 us; speedup vs baseline: 1.5648x; 1.0864x over previous
//
#include <hip/hip_runtime.h>
#include <cmath>

// ---------------------------------------------------------------------------
// EncoderLayer: x -> MHA -> +res -> LN1 -> FFN(GELU) -> +res -> LN2
// B=2 L=2048 D=1024 H=16 dk=64 F=4096  (M = B*L = 4096 rows)
// bf16 MFMA 16x16x32, fp32 accumulate, fp32 LN/residual.
// GEMM: 128xTN tile, BK=32, double-buffered LDS + global_load_lds(16B),
//       one barrier per chunk, prefetch in flight across compute (attn-style).
// Attention: S^T flash with LDS-staged double-buffered K/V tiles.
// ---------------------------------------------------------------------------

typedef unsigned short u16;
typedef unsigned int u32;
typedef __attribute__((ext_vector_type(8))) __bf16 bf16x8;
typedef __attribute__((ext_vector_type(4))) float f32x4;

#define MFMA16(a, b, c) __builtin_amdgcn_mfma_f32_16x16x32_bf16(a, b, c, 0, 0, 0)

__device__ __forceinline__ u16 f2bf(float f) {
  u32 u = __builtin_bit_cast(u32, f);
  u += 0x7fffu + ((u >> 16) & 1u);   // round-to-nearest-even
  return (u16)(u >> 16);
}

__device__ __forceinline__ u32 pack2bf(float lo, float hi) {
  return (u32)f2bf(lo) | ((u32)f2bf(hi) << 16);
}

__device__ __forceinline__ bf16x8 ld_frag(const u16* p) {
  return __builtin_bit_cast(bf16x8, *(const uint4*)p);
}

__device__ __forceinline__ float fexp2(float x) {
#if __has_builtin(__builtin_amdgcn_exp2f)
  return __builtin_amdgcn_exp2f(x);
#else
  return exp2f(x);
#endif
}

// async global->LDS, 16B per lane; LDS dest = wave-uniform base + lane*16
__device__ __forceinline__ void gload16(const u16* g, u16* l) {
  __builtin_amdgcn_global_load_lds(
      (const __attribute__((address_space(1))) void*)g,
      (__attribute__((address_space(3))) void*)l, 16, 0, 0);
}

// ---------------- fp32 -> bf16 elementwise convert (x) ----------------------
__global__ __launch_bounds__(256) void cvt_bf16_k(const float* __restrict__ src,
                                                  u16* __restrict__ dst) {
  int i = (blockIdx.x * 256 + threadIdx.x) * 4;
  float4 v = *(const float4*)(src + i);
  ushort4 o;
  o.x = f2bf(v.x); o.y = f2bf(v.y); o.z = f2bf(v.z); o.w = f2bf(v.w);
  *(ushort4*)(dst + i) = o;
}

// ---------------- fp32 [R][C] -> bf16 [C][R] transpose ----------------------
__global__ __launch_bounds__(256) void transpose_bf16_k(const float* __restrict__ src,
                                                        u16* __restrict__ dst,
                                                        int R, int C) {
  __shared__ float tile[32][33];
  int tx = threadIdx.x & 31, ty = threadIdx.x >> 5;  // 32 x 8
  int c0 = blockIdx.x * 32, r0 = blockIdx.y * 32;
#pragma unroll
  for (int i = 0; i < 4; i++)
    tile[ty + 8 * i][tx] = src[(long)(r0 + ty + 8 * i) * C + c0 + tx];
  __syncthreads();
#pragma unroll
  for (int i = 0; i < 4; i++)
    dst[(long)(c0 + ty + 8 * i) * R + r0 + tx] = f2bf(tile[tx][ty + 8 * i]);
}

// ---- 4x 1024x1024 fp32 -> bf16 transposes in one launch (z picks matrix) ---
__global__ __launch_bounds__(256) void transpose4_bf16_k(
    const float* __restrict__ Wq, const float* __restrict__ Wk,
    const float* __restrict__ Wv, const float* __restrict__ Wo,
    u16* __restrict__ wqkvT, u16* __restrict__ woT) {
  const int z = blockIdx.z;
  const float* src = (z == 0) ? Wq : (z == 1) ? Wk : (z == 2) ? Wv : Wo;
  u16* dst = (z < 3) ? (wqkvT + (size_t)z * 1024 * 1024) : woT;
  __shared__ float tile[32][33];
  int tx = threadIdx.x & 31, ty = threadIdx.x >> 5;
  int c0 = blockIdx.x * 32, r0 = blockIdx.y * 32;
#pragma unroll
  for (int i = 0; i < 4; i++)
    tile[ty + 8 * i][tx] = src[(long)(r0 + ty + 8 * i) * 1024 + c0 + tx];
  __syncthreads();
#pragma unroll
  for (int i = 0; i < 4; i++)
    dst[(long)(c0 + ty + 8 * i) * 1024 + r0 + tx] = f2bf(tile[tx][ty + 8 * i]);
}

// ---------------- GEMM: C[M][N] = A[M][K] * BT[N][K]^T ----------------------
// 128xTN block tile (TN = 128 or 64), BK=32, 4 waves in 2x2; wave tile
// 64 x TN/2. Double-buffered LDS, global_load_lds 16B, XOR-swizzled segs,
// ONE barrier per chunk; prefetch of chunk k+1 in flight across compute.
// MODE 0: QKV scatter epilogue; MODE 1: fp32+bias; MODE 2: bf16+bias+GELU.
template <int MODE, int TN>
__global__ __launch_bounds__(256) void gemm_k(
    const u16* __restrict__ A, const u16* __restrict__ BT, int M, int N, int K,
    const float* __restrict__ bias, float* __restrict__ outF, u16* __restrict__ outB,
    u16* __restrict__ qd, u16* __restrict__ kd, u16* __restrict__ vTd,
    const float* __restrict__ bq, const float* __restrict__ bk, const float* __restrict__ bv) {
  constexpr int NT = TN / 32;           // n-tiles per wave (4 or 2)
  __shared__ u16 As[2][128 * 32];
  __shared__ u16 Bs[2][TN * 32];
  const int tid = threadIdx.x;
  const int wave = tid >> 6, lane = tid & 63, quad = lane >> 4, l16 = lane & 15;
  const int wm = wave >> 1, wn = wave & 1;
  const int m0 = blockIdx.y * 128, n0 = blockIdx.x * TN;

  // staging: each issue = 16 rows x 1 seg(16B)/lane; seg XOR-swizzled by row
  const int srow = lane >> 2;                  // 0..15
  const int sxor = (lane & 3) ^ (srow & 3);    // swizzled source seg
  const u16* aS0 = A + (long)(m0 + wave * 32 + srow) * K + sxor * 8;
  const u16* aS1 = aS0 + 16 * K;
  const u16* bS0 = BT + (long)(n0 + (TN == 128 ? wave * 32 : wave * 16) + srow) * K + sxor * 8;
  const u16* bS1 = bS0 + 16 * K;  // used only when TN==128

  // fragment read offsets (u16 units): row*32 + (quad^(row&3))*8
  int aoff[4], boff[NT];
#pragma unroll
  for (int t = 0; t < 4; t++) {
    int ra = wm * 64 + t * 16 + l16;
    aoff[t] = ra * 32 + ((quad ^ (l16 & 3)) * 8);
  }
#pragma unroll
  for (int t = 0; t < NT; t++) {
    int rb = wn * (TN / 2) + t * 16 + l16;
    boff[t] = rb * 32 + ((quad ^ (l16 & 3)) * 8);
  }

  auto stage = [&](int buf, int k0) {
    gload16(aS0 + k0, &As[buf][(wave * 2 + 0) * 512]);
    gload16(aS1 + k0, &As[buf][(wave * 2 + 1) * 512]);
    if (TN == 128) {
      gload16(bS0 + k0, &Bs[buf][(wave * 2 + 0) * 512]);
      gload16(bS1 + k0, &Bs[buf][(wave * 2 + 1) * 512]);
    } else {
      gload16(bS0 + k0, &Bs[buf][wave * 512]);
    }
  };

  f32x4 acc[4][NT] = {};

  stage(0, 0);
#pragma unroll 1
  for (int k0 = 0; k0 < K; k0 += 32) {
    const int buf = (k0 >> 5) & 1;
    __syncthreads();                    // drains prefetch; prev reads done
    if (k0 + 32 < K) stage(buf ^ 1, k0 + 32);
    bf16x8 af[4], bfr[NT];
#pragma unroll
    for (int t = 0; t < 4; t++) af[t] = ld_frag(&As[buf][aoff[t]]);
#pragma unroll
    for (int t = 0; t < NT; t++) bfr[t] = ld_frag(&Bs[buf][boff[t]]);
#pragma unroll
    for (int mt = 0; mt < 4; mt++)
#pragma unroll
      for (int nt = 0; nt < NT; nt++)
        acc[mt][nt] = MFMA16(af[mt], bfr[nt], acc[mt][nt]);
  }

  if (MODE == 0) {
#pragma unroll
    for (int nt = 0; nt < NT; nt++) {
      int n = n0 + wn * (TN / 2) + nt * 16 + l16;
      int mat = n >> 10, nn = n & 1023, hh = nn >> 6, dd = nn & 63;
      const float* bp = (mat == 0) ? bq : ((mat == 1) ? bk : bv);
      float bb = bp[nn];
#pragma unroll
      for (int mt = 0; mt < 4; mt++) {
#pragma unroll
        for (int r = 0; r < 4; r++) {
          int mr = m0 + wm * 64 + mt * 16 + quad * 4 + r;
          int bI = mr >> 11, ll = mr & 2047;
          float v = acc[mt][nt][r] + bb;
          if (mat == 0) {
            // fold 1/sqrt(dk)*log2(e) so attention uses exp2 directly
            qd[((long)((bI * 16 + hh) * 2048 + ll)) * 64 + dd] = f2bf(v * 0.18033688011112043f);
          } else if (mat == 1) {
            kd[((long)((bI * 16 + hh) * 2048 + ll)) * 64 + dd] = f2bf(v);
          } else {
            vTd[((long)((bI * 16 + hh) * 64 + dd)) * 2048 + ll] = f2bf(v);
          }
        }
      }
    }
  } else if (MODE == 1) {
#pragma unroll
    for (int nt = 0; nt < NT; nt++) {
      int n = n0 + wn * (TN / 2) + nt * 16 + l16;
      float bb = bias[n];
#pragma unroll
      for (int mt = 0; mt < 4; mt++) {
#pragma unroll
        for (int r = 0; r < 4; r++) {
          int mr = m0 + wm * 64 + mt * 16 + quad * 4 + r;
          outF[(long)mr * N + n] = acc[mt][nt][r] + bb;
        }
      }
    }
  } else {
#pragma unroll
    for (int nt = 0; nt < NT; nt++) {
      int n = n0 + wn * (TN / 2) + nt * 16 + l16;
      float bb = bias[n];
#pragma unroll
      for (int mt = 0; mt < 4; mt++) {
#pragma unroll
        for (int r = 0; r < 4; r++) {
          int mr = m0 + wm * 64 + mt * 16 + quad * 4 + r;
          float v = acc[mt][nt][r] + bb;
          v = 0.5f * v * (1.0f + erff(v * 0.70710678118654752f));  // exact GELU
          outB[(long)mr * N + n] = f2bf(v);
        }
      }
    }
  }
}

// ---------------- flash attention (S^T, LDS-staged K/V) ---------------------
// grid (L/64, B*H), 4 waves; wave owns 16 q rows; 64-key chunks.
// K tile [64 key][64 dk], V tile [64 dk][64 key] (from vT), both 8KB bf16,
// XOR-swizzled segs (s^(row&7)), double-buffered, staged via global_load_lds.
// One __syncthreads per chunk; prefetch of chunk j+1 stays in flight across
// the softmax/PV body. q pre-scaled by 0.125*log2(e) -> p = exp2(s-m).
__global__ __launch_bounds__(256) void attn_k(const u16* __restrict__ qd,
                                              const u16* __restrict__ kd,
                                              const u16* __restrict__ vTd,
                                              u16* __restrict__ ctx) {
  __shared__ u16 Ks[2][64 * 64];
  __shared__ u16 Vs[2][64 * 64];
  __shared__ __align__(16) u16 P[4][16][72];  // per-wave P^T bounce
  const int tid = threadIdx.x;
  const int wave = tid >> 6, lane = tid & 63, quad = lane >> 4, l16 = lane & 15;
  const int bh = blockIdx.y;
  const u16* Q = qd + (long)bh * 2048 * 64;
  const u16* Kp = kd + (long)bh * 2048 * 64;
  const u16* Vt = vTd + (long)bh * 64 * 2048;
  const int qbase = blockIdx.x * 64 + wave * 16;

  // Q as B operand: lane holds Q[q=l16][d = quad*8+j], two dk halves
  bf16x8 qf0 = ld_frag(Q + (qbase + l16) * 64 + quad * 8);
  bf16x8 qf1 = ld_frag(Q + (qbase + l16) * 64 + 32 + quad * 8);

  f32x4 o[4] = {};            // O^T[d = nt*16+quad*4+r][q = l16]
  float m = -1e30f, l = 0.f;  // per q (= per l16), replicated across quads
  u16* prow = &P[wave][l16][0];

  // staging: issue i covers 8 rows (128B each): r = wave*16 + i*8 + lane/8
  const int srow = lane >> 3;                // 0..7
  const int sx = (lane & 7) ^ srow;          // swizzled source seg (16B units)
  const int kr0 = wave * 16 + srow;
  const int kr1 = wave * 16 + 8 + srow;

  // fragment seg offsets (u16 units): (g ^ (l16&7))*8
  const int fs0 = ((0 * 4 + quad) ^ (l16 & 7)) * 8;  // K dh=0
  const int fs1 = ((1 * 4 + quad) ^ (l16 & 7)) * 8;  // K dh=1
  const int vs0 = fs0;                               // V kh=0 (same formula)
  const int vs1 = fs1;                               // V kh=1

  auto stage = [&](int buf, int j0) {
    gload16(Kp + (long)(j0 + kr0) * 64 + sx * 8, &Ks[buf][(wave * 2 + 0) * 512]);
    gload16(Kp + (long)(j0 + kr1) * 64 + sx * 8, &Ks[buf][(wave * 2 + 1) * 512]);
    gload16(Vt + (long)kr0 * 2048 + j0 + sx * 8, &Vs[buf][(wave * 2 + 0) * 512]);
    gload16(Vt + (long)kr1 * 2048 + j0 + sx * 8, &Vs[buf][(wave * 2 + 1) * 512]);
  };

  stage(0, 0);

#pragma unroll 1
  for (int j0 = 0; j0 < 2048; j0 += 64) {
    const int buf = (j0 >> 6) & 1;
    __syncthreads();                       // staged chunk visible; prev body done
    if (j0 + 64 < 2048) stage(buf ^ 1, j0 + 64);

    // ---- S^T = K Q^T over 64 keys ----
    const u16* kb = &Ks[buf][0];
    f32x4 st[4];
#pragma unroll
    for (int f = 0; f < 4; f++) {
      bf16x8 k0 = ld_frag(kb + (f * 16 + l16) * 64 + fs0);
      bf16x8 k1 = ld_frag(kb + (f * 16 + l16) * 64 + fs1);
      f32x4 s = {};
      s = MFMA16(k0, qf0, s);
      s = MFMA16(k1, qf1, s);
      st[f] = s;
    }

    // ---- online softmax over the 64-key chunk (cross-quad reduce) ----
    float mx = -1e30f;
#pragma unroll
    for (int f = 0; f < 4; f++)
      mx = fmaxf(mx, fmaxf(fmaxf(st[f][0], st[f][1]), fmaxf(st[f][2], st[f][3])));
    mx = fmaxf(mx, __shfl_xor(mx, 16));
    mx = fmaxf(mx, __shfl_xor(mx, 32));
    float mn = fmaxf(m, mx);
    float al = fexp2(m - mn);
    float p[4][4];
    float sm = 0.f;
#pragma unroll
    for (int f = 0; f < 4; f++) {
#pragma unroll
      for (int r = 0; r < 4; r++) {
        p[f][r] = fexp2(st[f][r] - mn);
        sm += p[f][r];
      }
    }
    sm += __shfl_xor(sm, 16);
    sm += __shfl_xor(sm, 32);
    l = l * al + sm;
    m = mn;
#pragma unroll
    for (int nt = 0; nt < 4; nt++) {
      o[nt][0] *= al; o[nt][1] *= al; o[nt][2] *= al; o[nt][3] *= al;
    }

    // ---- pack P^T to bf16, per-wave LDS bounce [q][key] ----
#pragma unroll
    for (int f = 0; f < 4; f++) {
      uint2 u;
      u.x = pack2bf(p[f][0], p[f][1]);
      u.y = pack2bf(p[f][2], p[f][3]);
      *(uint2*)(prow + f * 16 + quad * 4) = u;
    }
    // wave-internal write->read ordering (no inter-wave dep, no barrier)
    __asm__ volatile("s_waitcnt lgkmcnt(0)" ::: "memory");

    // ---- O^T += V^T P^T ----
    const u16* vb = &Vs[buf][0];
#pragma unroll
    for (int kh = 0; kh < 2; kh++) {
      bf16x8 pf = ld_frag(prow + kh * 32 + quad * 8);
      const int vss = kh ? vs1 : vs0;
#pragma unroll
      for (int nt = 0; nt < 4; nt++) {
        o[nt] = MFMA16(ld_frag(vb + (nt * 16 + l16) * 64 + vss), pf, o[nt]);
      }
    }
  }

  // ---- epilogue: divide by l, write ctx[b][l][h*64+d] ----
  const int bI = bh >> 4, hh = bh & 15;
  const float rl = 1.0f / l;
  const long row = (long)(bI * 2048 + qbase + l16);
#pragma unroll
  for (int nt = 0; nt < 4; nt++) {
    ushort4 w;
    w.x = f2bf(o[nt][0] * rl);
    w.y = f2bf(o[nt][1] * rl);
    w.z = f2bf(o[nt][2] * rl);
    w.w = f2bf(o[nt][3] * rl);
    *(ushort4*)(ctx + row * 1024 + hh * 64 + nt * 16 + quad * 4) = w;
  }
}

// ---------------- residual + LayerNorm -------------------------------------
__global__ __launch_bounds__(256) void ln_k(const float* __restrict__ a,
                                            const float* __restrict__ b,
                                            const float* __restrict__ g,
                                            const float* __restrict__ be,
                                            float* __restrict__ outF,
                                            u16* __restrict__ outB) {
  const int row = blockIdx.x, tid = threadIdx.x;
  const float* pa = a + (long)row * 1024;
  const float* pb = b + (long)row * 1024;
  float v[4], s = 0.f, sq = 0.f;
#pragma unroll
  for (int i = 0; i < 4; i++) {
    int c = i * 256 + tid;
    v[i] = pa[c] + pb[c];
    s += v[i];
    sq += v[i] * v[i];
  }
#pragma unroll
  for (int off = 1; off < 64; off <<= 1) {
    s += __shfl_xor(s, off);
    sq += __shfl_xor(sq, off);
  }
  __shared__ float red[10];
  int wave = tid >> 6, lane = tid & 63;
  if (lane == 0) { red[wave * 2] = s; red[wave * 2 + 1] = sq; }
  __syncthreads();
  if (tid == 0) {
    float S = red[0] + red[2] + red[4] + red[6];
    float Q = red[1] + red[3] + red[5] + red[7];
    float mu = S * (1.0f / 1024.0f);
    float var = Q * (1.0f / 1024.0f) - mu * mu;
    red[8] = mu;
    red[9] = rsqrtf(var + 1e-5f);
  }
  __syncthreads();
  float mu = red[8], rstd = red[9];
#pragma unroll
  for (int i = 0; i < 4; i++) {
    int c = i * 256 + tid;
    float o = (v[i] - mu) * rstd * g[c] + be[c];
    outF[(long)row * 1024 + c] = o;
    if (outB) outB[(long)row * 1024 + c] = f2bf(o);
  }
}

// ---------------------------------------------------------------------------
extern "C" void kernel_launch(void* const* d_in, const int* in_sizes, int n_in,
                              void* d_out, int out_size, void* d_ws, size_t ws_size,
                              hipStream_t stream) {
  const float* x  = (const float*)d_in[0];
  const float* Wq = (const float*)d_in[1];  const float* bq = (const float*)d_in[2];
  const float* Wk = (const float*)d_in[3];  const float* bk = (const float*)d_in[4];
  const float* Wv = (const float*)d_in[5];  const float* bv = (const float*)d_in[6];
  const float* Wo = (const float*)d_in[7];  const float* bo = (const float*)d_in[8];
  const float* W1 = (const float*)d_in[9];  const float* b1 = (const float*)d_in[10];
  const float* W2 = (const float*)d_in[11]; const float* b2 = (const float*)d_in[12];
  const float* g1 = (const float*)d_in[13]; const float* be1 = (const float*)d_in[14];
  const float* g2 = (const float*)d_in[15]; const float* be2 = (const float*)d_in[16];

  char* ws = (char*)d_ws;
  size_t off = 0;
  auto alloc = [&](size_t bytes) {
    size_t o = off;
    off += (bytes + 255) & ~(size_t)255;
    return o;
  };
  u16*   xb     = (u16*)(ws + alloc(4096UL * 1024 * 2));
  u16*   wqkvT  = (u16*)(ws + alloc(3072UL * 1024 * 2));
  u16*   woT    = (u16*)(ws + alloc(1024UL * 1024 * 2));
  u16*   w1T    = (u16*)(ws + alloc(4096UL * 1024 * 2));
  u16*   w2T    = (u16*)(ws + alloc(1024UL * 4096 * 2));
  u16*   qb     = (u16*)(ws + alloc(32UL * 2048 * 64 * 2));
  u16*   kb     = (u16*)(ws + alloc(32UL * 2048 * 64 * 2));
  u16*   vTb    = (u16*)(ws + alloc(32UL * 64 * 2048 * 2));
  u16*   ctx    = (u16*)(ws + alloc(4096UL * 1024 * 2));
  float* attnO  = (float*)(ws + alloc(4096UL * 1024 * 4));
  float* h      = (float*)(ws + alloc(4096UL * 1024 * 4));
  u16*   hb     = (u16*)(ws + alloc(4096UL * 1024 * 2));
  u16*   ff1    = (u16*)(ws + alloc(4096UL * 4096 * 2));
  float* ff2    = (float*)(ws + alloc(4096UL * 1024 * 4));
  if (off > ws_size) return;  // workspace too small: bail (bench will flag)

  // 1) bf16 conversions / weight transposes
  cvt_bf16_k<<<4096, 256, 0, stream>>>(x, xb);
  transpose4_bf16_k<<<dim3(32, 32, 4), 256, 0, stream>>>(Wq, Wk, Wv, Wo, wqkvT, woT);
  transpose_bf16_k<<<dim3(128, 32), 256, 0, stream>>>(W1, w1T, 1024, 4096);
  transpose_bf16_k<<<dim3(32, 128), 256, 0, stream>>>(W2, w2T, 4096, 1024);

  // 2) QKV projection (N=3072 fused), scatter epilogue
  gemm_k<0, 128><<<dim3(24, 32), 256, 0, stream>>>(xb, wqkvT, 4096, 3072, 1024,
                                                   nullptr, nullptr, nullptr,
                                                   qb, kb, vTb, bq, bk, bv);
  // 3) attention
  attn_k<<<dim3(32, 32), 256, 0, stream>>>(qb, kb, vTb, ctx);
  // 4) output projection (N=1024: TN=64 -> 512 blocks)
  gemm_k<1, 64><<<dim3(16, 32), 256, 0, stream>>>(ctx, woT, 4096, 1024, 1024,
                                                  bo, attnO, nullptr,
                                                  nullptr, nullptr, nullptr, nullptr, nullptr, nullptr);
  // 5) residual + LN1 (fp32 h + bf16 hb)
  ln_k<<<4096, 256, 0, stream>>>(x, attnO, g1, be1, h, hb);
  // 6) FFN up + GELU
  gemm_k<2, 128><<<dim3(32, 32), 256, 0, stream>>>(hb, w1T, 4096, 4096, 1024,
                                                   b1, nullptr, ff1,
                                                   nullptr, nullptr, nullptr, nullptr, nullptr, nullptr);
  // 7) FFN down (N=1024: TN=64 -> 512 blocks)
  gemm_k<1, 64><<<dim3(16, 32), 256, 0, stream>>>(ff1, w2T, 4096, 1024, 4096,
                                                  b2, ff2, nullptr,
                                                  nullptr, nullptr, nullptr, nullptr, nullptr, nullptr);
  // 8) residual + LN2 -> out
  ln_k<<<4096, 256, 0, stream>>>(h, ff2, g2, be2, (float*)d_out, nullptr);
}

// Round 6
// 426.554 us; speedup vs baseline: 1.6508x; 1.0550x over previous
//
#include <hip/hip_runtime.h>
#include <cmath>

// ---------------------------------------------------------------------------
// EncoderLayer: x -> MHA -> +res -> LN1 -> FFN(GELU) -> +res -> LN2
// B=2 L=2048 D=1024 H=16 dk=64 F=4096  (M = B*L = 4096 rows)
// bf16 MFMA 16x16x32, fp32 accumulate, fp32 LN/residual.
// GEMM: 128xTN dbuf global_load_lds pipeline + XCD/group-m block swizzle.
// Attention: S^T flash, 128 q/block (32 q/wave), dbuf K/V LDS staging,
//            perm-packed P, ballot-gated rescale.
// ---------------------------------------------------------------------------

typedef unsigned short u16;
typedef unsigned int u32;
typedef __attribute__((ext_vector_type(8))) __bf16 bf16x8;
typedef __attribute__((ext_vector_type(4))) float f32x4;

#define MFMA16(a, b, c) __builtin_amdgcn_mfma_f32_16x16x32_bf16(a, b, c, 0, 0, 0)

__device__ __forceinline__ u16 f2bf(float f) {
  u32 u = __builtin_bit_cast(u32, f);
  u += 0x7fffu + ((u >> 16) & 1u);   // round-to-nearest-even
  return (u16)(u >> 16);
}

// truncation-pack two fp32 -> bf16x2 in ONE v_perm_b32
__device__ __forceinline__ u32 packtrunc(float lo, float hi) {
#if __has_builtin(__builtin_amdgcn_perm)
  return __builtin_amdgcn_perm(__builtin_bit_cast(u32, hi),
                               __builtin_bit_cast(u32, lo), 0x07060302u);
#else
  return (__builtin_bit_cast(u32, lo) >> 16) |
         (__builtin_bit_cast(u32, hi) & 0xFFFF0000u);
#endif
}

__device__ __forceinline__ bf16x8 ld_frag(const u16* p) {
  return __builtin_bit_cast(bf16x8, *(const uint4*)p);
}

__device__ __forceinline__ float fexp2(float x) {
#if __has_builtin(__builtin_amdgcn_exp2f)
  return __builtin_amdgcn_exp2f(x);
#else
  return exp2f(x);
#endif
}

// async global->LDS, 16B per lane; LDS dest = wave-uniform base + lane*16
__device__ __forceinline__ void gload16(const u16* g, u16* l) {
  __builtin_amdgcn_global_load_lds(
      (const __attribute__((address_space(1))) void*)g,
      (__attribute__((address_space(3))) void*)l, 16, 0, 0);
}

// XCD-aware + group-m(8) tile swizzle. Requires gridDim.x*gridDim.y % 8 == 0
// and gridDim.y % 8 == 0 (true for all launches here).
__device__ __forceinline__ void tile_coords(int& pm, int& pn) {
  int nb = gridDim.x * gridDim.y;
  int id = blockIdx.y * gridDim.x + blockIdx.x;
  // give each XCD (id % 8, heuristic) a contiguous range of tile-space
  int w = (id & 7) * (nb >> 3) + (id >> 3);
  // group-m decode: within a group of 8 m-tiles, m varies fastest
  int gsz = 8 * gridDim.x;
  int first = (w / gsz) * 8;
  int loc = w % gsz;
  pm = first + (loc & 7);
  pn = loc >> 3;
}

// ---------------- fp32 -> bf16 elementwise convert (x) ----------------------
__global__ __launch_bounds__(256) void cvt_bf16_k(const float* __restrict__ src,
                                                  u16* __restrict__ dst) {
  int i = (blockIdx.x * 256 + threadIdx.x) * 4;
  float4 v = *(const float4*)(src + i);
  ushort4 o;
  o.x = f2bf(v.x); o.y = f2bf(v.y); o.z = f2bf(v.z); o.w = f2bf(v.w);
  *(ushort4*)(dst + i) = o;
}

// ---------------- fp32 [R][C] -> bf16 [C][R] transpose ----------------------
__global__ __launch_bounds__(256) void transpose_bf16_k(const float* __restrict__ src,
                                                        u16* __restrict__ dst,
                                                        int R, int C) {
  __shared__ float tile[32][33];
  int tx = threadIdx.x & 31, ty = threadIdx.x >> 5;  // 32 x 8
  int c0 = blockIdx.x * 32, r0 = blockIdx.y * 32;
#pragma unroll
  for (int i = 0; i < 4; i++)
    tile[ty + 8 * i][tx] = src[(long)(r0 + ty + 8 * i) * C + c0 + tx];
  __syncthreads();
#pragma unroll
  for (int i = 0; i < 4; i++)
    dst[(long)(c0 + ty + 8 * i) * R + r0 + tx] = f2bf(tile[tx][ty + 8 * i]);
}

// ---- 4x 1024x1024 fp32 -> bf16 transposes in one launch (z picks matrix) ---
__global__ __launch_bounds__(256) void transpose4_bf16_k(
    const float* __restrict__ Wq, const float* __restrict__ Wk,
    const float* __restrict__ Wv, const float* __restrict__ Wo,
    u16* __restrict__ wqkvT, u16* __restrict__ woT) {
  const int z = blockIdx.z;
  const float* src = (z == 0) ? Wq : (z == 1) ? Wk : (z == 2) ? Wv : Wo;
  u16* dst = (z < 3) ? (wqkvT + (size_t)z * 1024 * 1024) : woT;
  __shared__ float tile[32][33];
  int tx = threadIdx.x & 31, ty = threadIdx.x >> 5;
  int c0 = blockIdx.x * 32, r0 = blockIdx.y * 32;
#pragma unroll
  for (int i = 0; i < 4; i++)
    tile[ty + 8 * i][tx] = src[(long)(r0 + ty + 8 * i) * 1024 + c0 + tx];
  __syncthreads();
#pragma unroll
  for (int i = 0; i < 4; i++)
    dst[(long)(c0 + ty + 8 * i) * 1024 + r0 + tx] = f2bf(tile[tx][ty + 8 * i]);
}

// ---------------- GEMM: C[M][N] = A[M][K] * BT[N][K]^T ----------------------
// 128xTN block tile (TN = 128 or 64), BK=32, 4 waves in 2x2; wave tile
// 64 x TN/2. Double-buffered LDS, global_load_lds 16B, XOR-swizzled segs,
// ONE barrier per chunk; prefetch of chunk k+1 in flight across compute.
// MODE 0: QKV scatter epilogue; MODE 1: fp32+bias; MODE 2: bf16+bias+GELU.
template <int MODE, int TN>
__global__ __launch_bounds__(256) void gemm_k(
    const u16* __restrict__ A, const u16* __restrict__ BT, int M, int N, int K,
    const float* __restrict__ bias, float* __restrict__ outF, u16* __restrict__ outB,
    u16* __restrict__ qd, u16* __restrict__ kd, u16* __restrict__ vTd,
    const float* __restrict__ bq, const float* __restrict__ bk, const float* __restrict__ bv) {
  constexpr int NT = TN / 32;           // n-tiles per wave (4 or 2)
  __shared__ u16 As[2][128 * 32];
  __shared__ u16 Bs[2][TN * 32];
  const int tid = threadIdx.x;
  const int wave = tid >> 6, lane = tid & 63, quad = lane >> 4, l16 = lane & 15;
  const int wm = wave >> 1, wn = wave & 1;
  int pm, pn;
  tile_coords(pm, pn);
  const int m0 = pm * 128, n0 = pn * TN;

  // staging: each issue = 16 rows x 1 seg(16B)/lane; seg XOR-swizzled by row
  const int srow = lane >> 2;                  // 0..15
  const int sxor = (lane & 3) ^ (srow & 3);    // swizzled source seg
  const u16* aS0 = A + (long)(m0 + wave * 32 + srow) * K + sxor * 8;
  const u16* aS1 = aS0 + 16 * K;
  const u16* bS0 = BT + (long)(n0 + (TN == 128 ? wave * 32 : wave * 16) + srow) * K + sxor * 8;
  const u16* bS1 = bS0 + 16 * K;  // used only when TN==128

  // fragment read offsets (u16 units): row*32 + (quad^(row&3))*8
  int aoff[4], boff[NT];
#pragma unroll
  for (int t = 0; t < 4; t++) {
    int ra = wm * 64 + t * 16 + l16;
    aoff[t] = ra * 32 + ((quad ^ (l16 & 3)) * 8);
  }
#pragma unroll
  for (int t = 0; t < NT; t++) {
    int rb = wn * (TN / 2) + t * 16 + l16;
    boff[t] = rb * 32 + ((quad ^ (l16 & 3)) * 8);
  }

  auto stage = [&](int buf, int k0) {
    gload16(aS0 + k0, &As[buf][(wave * 2 + 0) * 512]);
    gload16(aS1 + k0, &As[buf][(wave * 2 + 1) * 512]);
    if (TN == 128) {
      gload16(bS0 + k0, &Bs[buf][(wave * 2 + 0) * 512]);
      gload16(bS1 + k0, &Bs[buf][(wave * 2 + 1) * 512]);
    } else {
      gload16(bS0 + k0, &Bs[buf][wave * 512]);
    }
  };

  f32x4 acc[4][NT] = {};

  stage(0, 0);
#pragma unroll 1
  for (int k0 = 0; k0 < K; k0 += 32) {
    const int buf = (k0 >> 5) & 1;
    __syncthreads();                    // drains prefetch; prev reads done
    if (k0 + 32 < K) stage(buf ^ 1, k0 + 32);
    bf16x8 af[4], bfr[NT];
#pragma unroll
    for (int t = 0; t < 4; t++) af[t] = ld_frag(&As[buf][aoff[t]]);
#pragma unroll
    for (int t = 0; t < NT; t++) bfr[t] = ld_frag(&Bs[buf][boff[t]]);
#pragma unroll
    for (int mt = 0; mt < 4; mt++)
#pragma unroll
      for (int nt = 0; nt < NT; nt++)
        acc[mt][nt] = MFMA16(af[mt], bfr[nt], acc[mt][nt]);
  }

  if (MODE == 0) {
#pragma unroll
    for (int nt = 0; nt < NT; nt++) {
      int n = n0 + wn * (TN / 2) + nt * 16 + l16;
      int mat = n >> 10, nn = n & 1023, hh = nn >> 6, dd = nn & 63;
      const float* bp = (mat == 0) ? bq : ((mat == 1) ? bk : bv);
      float bb = bp[nn];
#pragma unroll
      for (int mt = 0; mt < 4; mt++) {
#pragma unroll
        for (int r = 0; r < 4; r++) {
          int mr = m0 + wm * 64 + mt * 16 + quad * 4 + r;
          int bI = mr >> 11, ll = mr & 2047;
          float v = acc[mt][nt][r] + bb;
          if (mat == 0) {
            // fold 1/sqrt(dk)*log2(e) so attention uses exp2 directly
            qd[((long)((bI * 16 + hh) * 2048 + ll)) * 64 + dd] = f2bf(v * 0.18033688011112043f);
          } else if (mat == 1) {
            kd[((long)((bI * 16 + hh) * 2048 + ll)) * 64 + dd] = f2bf(v);
          } else {
            vTd[((long)((bI * 16 + hh) * 64 + dd)) * 2048 + ll] = f2bf(v);
          }
        }
      }
    }
  } else if (MODE == 1) {
#pragma unroll
    for (int nt = 0; nt < NT; nt++) {
      int n = n0 + wn * (TN / 2) + nt * 16 + l16;
      float bb = bias[n];
#pragma unroll
      for (int mt = 0; mt < 4; mt++) {
#pragma unroll
        for (int r = 0; r < 4; r++) {
          int mr = m0 + wm * 64 + mt * 16 + quad * 4 + r;
          outF[(long)mr * N + n] = acc[mt][nt][r] + bb;
        }
      }
    }
  } else {
#pragma unroll
    for (int nt = 0; nt < NT; nt++) {
      int n = n0 + wn * (TN / 2) + nt * 16 + l16;
      float bb = bias[n];
#pragma unroll
      for (int mt = 0; mt < 4; mt++) {
#pragma unroll
        for (int r = 0; r < 4; r++) {
          int mr = m0 + wm * 64 + mt * 16 + quad * 4 + r;
          float v = acc[mt][nt][r] + bb;
          v = 0.5f * v * (1.0f + erff(v * 0.70710678118654752f));  // exact GELU
          outB[(long)mr * N + n] = f2bf(v);
        }
      }
    }
  }
}

// ---------------- flash attention (S^T, LDS-staged K/V) ---------------------
// grid (L/128, B*H), 4 waves; wave owns 32 q rows (two 16-q sets); 64-key
// chunks. K tile [64 key][64 dk], V tile [64 dk][64 key], XOR-swizzled,
// double-buffered, global_load_lds staged. One barrier per chunk.
// q pre-scaled by 0.125*log2(e) -> p = exp2(s-m). P packed by truncation
// (single v_perm per pair). o-rescale gated by wave-uniform ballot.
__global__ __launch_bounds__(256) void attn_k(const u16* __restrict__ qd,
                                              const u16* __restrict__ kd,
                                              const u16* __restrict__ vTd,
                                              u16* __restrict__ ctx) {
  __shared__ u16 Ks[2][64 * 64];
  __shared__ u16 Vs[2][64 * 64];
  __shared__ __align__(16) u16 P[4][32][72];  // per-wave P^T bounce
  const int tid = threadIdx.x;
  const int wave = tid >> 6, lane = tid & 63, quad = lane >> 4, l16 = lane & 15;
  const int bh = blockIdx.y;
  const u16* Q = qd + (long)bh * 2048 * 64;
  const u16* Kp = kd + (long)bh * 2048 * 64;
  const u16* Vt = vTd + (long)bh * 64 * 2048;
  const int qbase = blockIdx.x * 128 + wave * 32;

  // Q as B operand: lane holds Q[q=l16][d = quad*8+j], two q-sets x two halves
  bf16x8 qf[2][2];
#pragma unroll
  for (int qs = 0; qs < 2; qs++) {
    qf[qs][0] = ld_frag(Q + (qbase + qs * 16 + l16) * 64 + quad * 8);
    qf[qs][1] = ld_frag(Q + (qbase + qs * 16 + l16) * 64 + 32 + quad * 8);
  }

  f32x4 o[2][4] = {};              // O^T[d = nt*16+quad*4+r][q = l16] per set
  float m[2] = {-1e30f, -1e30f}, l[2] = {0.f, 0.f};

  // staging: issue i covers 8 rows (128B each): r = wave*16 + i*8 + lane/8
  const int srow = lane >> 3;                // 0..7
  const int sx = (lane & 7) ^ srow;          // swizzled source seg (16B units)
  const int kr0 = wave * 16 + srow;
  const int kr1 = wave * 16 + 8 + srow;

  // fragment seg offsets (u16 units): (g ^ (l16&7))*8
  const int fs0 = ((0 * 4 + quad) ^ (l16 & 7)) * 8;
  const int fs1 = ((1 * 4 + quad) ^ (l16 & 7)) * 8;

  auto stage = [&](int buf, int j0) {
    gload16(Kp + (long)(j0 + kr0) * 64 + sx * 8, &Ks[buf][(wave * 2 + 0) * 512]);
    gload16(Kp + (long)(j0 + kr1) * 64 + sx * 8, &Ks[buf][(wave * 2 + 1) * 512]);
    gload16(Vt + (long)kr0 * 2048 + j0 + sx * 8, &Vs[buf][(wave * 2 + 0) * 512]);
    gload16(Vt + (long)kr1 * 2048 + j0 + sx * 8, &Vs[buf][(wave * 2 + 1) * 512]);
  };

  stage(0, 0);

#pragma unroll 1
  for (int j0 = 0; j0 < 2048; j0 += 64) {
    const int buf = (j0 >> 6) & 1;
    __syncthreads();                       // staged chunk visible; prev body done
    if (j0 + 64 < 2048) stage(buf ^ 1, j0 + 64);

    // ---- S^T = K Q^T over 64 keys, both q-sets (K frags shared) ----
    const u16* kb = &Ks[buf][0];
    f32x4 st[2][4];
#pragma unroll
    for (int f = 0; f < 4; f++) {
      bf16x8 k0 = ld_frag(kb + (f * 16 + l16) * 64 + fs0);
      bf16x8 k1 = ld_frag(kb + (f * 16 + l16) * 64 + fs1);
      f32x4 s0 = {}, s1 = {};
      s0 = MFMA16(k0, qf[0][0], s0); s0 = MFMA16(k1, qf[0][1], s0);
      s1 = MFMA16(k0, qf[1][0], s1); s1 = MFMA16(k1, qf[1][1], s1);
      st[0][f] = s0; st[1][f] = s1;
    }

    // ---- online softmax per q-set ----
#pragma unroll
    for (int qs = 0; qs < 2; qs++) {
      float mx = -1e30f;
#pragma unroll
      for (int f = 0; f < 4; f++)
        mx = fmaxf(mx, fmaxf(fmaxf(st[qs][f][0], st[qs][f][1]),
                             fmaxf(st[qs][f][2], st[qs][f][3])));
      mx = fmaxf(mx, __shfl_xor(mx, 16));
      mx = fmaxf(mx, __shfl_xor(mx, 32));
      if (__ballot(mx > m[qs])) {        // wave-uniform; exact (al==1 otherwise)
        float mn = fmaxf(m[qs], mx);
        float al = fexp2(m[qs] - mn);
        m[qs] = mn;
        l[qs] *= al;
#pragma unroll
        for (int nt = 0; nt < 4; nt++) {
          o[qs][nt][0] *= al; o[qs][nt][1] *= al;
          o[qs][nt][2] *= al; o[qs][nt][3] *= al;
        }
      }
      float sm = 0.f;
      u16* prow = &P[wave][qs * 16 + l16][0];
#pragma unroll
      for (int f = 0; f < 4; f++) {
        float p0 = fexp2(st[qs][f][0] - m[qs]);
        float p1 = fexp2(st[qs][f][1] - m[qs]);
        float p2 = fexp2(st[qs][f][2] - m[qs]);
        float p3 = fexp2(st[qs][f][3] - m[qs]);
        sm += (p0 + p1) + (p2 + p3);
        uint2 u;
        u.x = packtrunc(p0, p1);
        u.y = packtrunc(p2, p3);
        *(uint2*)(prow + f * 16 + quad * 4) = u;
      }
      sm += __shfl_xor(sm, 16);
      sm += __shfl_xor(sm, 32);
      l[qs] += sm;
    }
    // wave-internal write->read ordering (no inter-wave dep, no barrier)
    __asm__ volatile("s_waitcnt lgkmcnt(0)" ::: "memory");

    // ---- O^T += V^T P^T (V frags shared across q-sets) ----
    const u16* vb = &Vs[buf][0];
    bf16x8 vf[4][2];
#pragma unroll
    for (int nt = 0; nt < 4; nt++) {
      vf[nt][0] = ld_frag(vb + (nt * 16 + l16) * 64 + fs0);
      vf[nt][1] = ld_frag(vb + (nt * 16 + l16) * 64 + fs1);
    }
#pragma unroll
    for (int qs = 0; qs < 2; qs++) {
      const u16* prow = &P[wave][qs * 16 + l16][0];
#pragma unroll
      for (int kh = 0; kh < 2; kh++) {
        bf16x8 pf = ld_frag(prow + kh * 32 + quad * 8);
#pragma unroll
        for (int nt = 0; nt < 4; nt++)
          o[qs][nt] = MFMA16(vf[nt][kh], pf, o[qs][nt]);
      }
    }
  }

  // ---- epilogue: divide by l, write ctx[b][l][h*64+d] ----
  const int bI = bh >> 4, hh = bh & 15;
#pragma unroll
  for (int qs = 0; qs < 2; qs++) {
    const float rl = 1.0f / l[qs];
    const long row = (long)(bI * 2048 + qbase + qs * 16 + l16);
#pragma unroll
    for (int nt = 0; nt < 4; nt++) {
      ushort4 w;
      w.x = f2bf(o[qs][nt][0] * rl);
      w.y = f2bf(o[qs][nt][1] * rl);
      w.z = f2bf(o[qs][nt][2] * rl);
      w.w = f2bf(o[qs][nt][3] * rl);
      *(ushort4*)(ctx + row * 1024 + hh * 64 + nt * 16 + quad * 4) = w;
    }
  }
}

// ---------------- residual + LayerNorm -------------------------------------
__global__ __launch_bounds__(256) void ln_k(const float* __restrict__ a,
                                            const float* __restrict__ b,
                                            const float* __restrict__ g,
                                            const float* __restrict__ be,
                                            float* __restrict__ outF,
                                            u16* __restrict__ outB) {
  const int row = blockIdx.x, tid = threadIdx.x;
  const float* pa = a + (long)row * 1024;
  const float* pb = b + (long)row * 1024;
  float v[4], s = 0.f, sq = 0.f;
#pragma unroll
  for (int i = 0; i < 4; i++) {
    int c = i * 256 + tid;
    v[i] = pa[c] + pb[c];
    s += v[i];
    sq += v[i] * v[i];
  }
#pragma unroll
  for (int off = 1; off < 64; off <<= 1) {
    s += __shfl_xor(s, off);
    sq += __shfl_xor(sq, off);
  }
  __shared__ float red[10];
  int wave = tid >> 6, lane = tid & 63;
  if (lane == 0) { red[wave * 2] = s; red[wave * 2 + 1] = sq; }
  __syncthreads();
  if (tid == 0) {
    float S = red[0] + red[2] + red[4] + red[6];
    float Q = red[1] + red[3] + red[5] + red[7];
    float mu = S * (1.0f / 1024.0f);
    float var = Q * (1.0f / 1024.0f) - mu * mu;
    red[8] = mu;
    red[9] = rsqrtf(var + 1e-5f);
  }
  __syncthreads();
  float mu = red[8], rstd = red[9];
#pragma unroll
  for (int i = 0; i < 4; i++) {
    int c = i * 256 + tid;
    float o = (v[i] - mu) * rstd * g[c] + be[c];
    outF[(long)row * 1024 + c] = o;
    if (outB) outB[(long)row * 1024 + c] = f2bf(o);
  }
}

// ---------------------------------------------------------------------------
extern "C" void kernel_launch(void* const* d_in, const int* in_sizes, int n_in,
                              void* d_out, int out_size, void* d_ws, size_t ws_size,
                              hipStream_t stream) {
  const float* x  = (const float*)d_in[0];
  const float* Wq = (const float*)d_in[1];  const float* bq = (const float*)d_in[2];
  const float* Wk = (const float*)d_in[3];  const float* bk = (const float*)d_in[4];
  const float* Wv = (const float*)d_in[5];  const float* bv = (const float*)d_in[6];
  const float* Wo = (const float*)d_in[7];  const float* bo = (const float*)d_in[8];
  const float* W1 = (const float*)d_in[9];  const float* b1 = (const float*)d_in[10];
  const float* W2 = (const float*)d_in[11]; const float* b2 = (const float*)d_in[12];
  const float* g1 = (const float*)d_in[13]; const float* be1 = (const float*)d_in[14];
  const float* g2 = (const float*)d_in[15]; const float* be2 = (const float*)d_in[16];

  char* ws = (char*)d_ws;
  size_t off = 0;
  auto alloc = [&](size_t bytes) {
    size_t o = off;
    off += (bytes + 255) & ~(size_t)255;
    return o;
  };
  u16*   xb     = (u16*)(ws + alloc(4096UL * 1024 * 2));
  u16*   wqkvT  = (u16*)(ws + alloc(3072UL * 1024 * 2));
  u16*   woT    = (u16*)(ws + alloc(1024UL * 1024 * 2));
  u16*   w1T    = (u16*)(ws + alloc(4096UL * 1024 * 2));
  u16*   w2T    = (u16*)(ws + alloc(1024UL * 4096 * 2));
  u16*   qb     = (u16*)(ws + alloc(32UL * 2048 * 64 * 2));
  u16*   kb     = (u16*)(ws + alloc(32UL * 2048 * 64 * 2));
  u16*   vTb    = (u16*)(ws + alloc(32UL * 64 * 2048 * 2));
  u16*   ctx    = (u16*)(ws + alloc(4096UL * 1024 * 2));
  float* attnO  = (float*)(ws + alloc(4096UL * 1024 * 4));
  float* h      = (float*)(ws + alloc(4096UL * 1024 * 4));
  u16*   hb     = (u16*)(ws + alloc(4096UL * 1024 * 2));
  u16*   ff1    = (u16*)(ws + alloc(4096UL * 4096 * 2));
  float* ff2    = (float*)(ws + alloc(4096UL * 1024 * 4));
  if (off > ws_size) return;  // workspace too small: bail (bench will flag)

  // 1) bf16 conversions / weight transposes
  cvt_bf16_k<<<4096, 256, 0, stream>>>(x, xb);
  transpose4_bf16_k<<<dim3(32, 32, 4), 256, 0, stream>>>(Wq, Wk, Wv, Wo, wqkvT, woT);
  transpose_bf16_k<<<dim3(128, 32), 256, 0, stream>>>(W1, w1T, 1024, 4096);
  transpose_bf16_k<<<dim3(32, 128), 256, 0, stream>>>(W2, w2T, 4096, 1024);

  // 2) QKV projection (N=3072 fused), scatter epilogue
  gemm_k<0, 128><<<dim3(24, 32), 256, 0, stream>>>(xb, wqkvT, 4096, 3072, 1024,
                                                   nullptr, nullptr, nullptr,
                                                   qb, kb, vTb, bq, bk, bv);
  // 3) attention (128 q per block)
  attn_k<<<dim3(16, 32), 256, 0, stream>>>(qb, kb, vTb, ctx);
  // 4) output projection (N=1024: TN=64 -> 512 blocks)
  gemm_k<1, 64><<<dim3(16, 32), 256, 0, stream>>>(ctx, woT, 4096, 1024, 1024,
                                                  bo, attnO, nullptr,
                                                  nullptr, nullptr, nullptr, nullptr, nullptr, nullptr);
  // 5) residual + LN1 (fp32 h + bf16 hb)
  ln_k<<<4096, 256, 0, stream>>>(x, attnO, g1, be1, h, hb);
  // 6) FFN up + GELU
  gemm_k<2, 128><<<dim3(32, 32), 256, 0, stream>>>(hb, w1T, 4096, 4096, 1024,
                                                   b1, nullptr, ff1,
                                                   nullptr, nullptr, nullptr, nullptr, nullptr, nullptr);
  // 7) FFN down (N=1024: TN=64 -> 512 blocks)
  gemm_k<1, 64><<<dim3(16, 32), 256, 0, stream>>>(ff1, w2T, 4096, 1024, 4096,
                                                  b2, ff2, nullptr,
                                                  nullptr, nullptr, nullptr, nullptr, nullptr, nullptr);
  // 8) residual + LN2 -> out
  ln_k<<<4096, 256, 0, stream>>>(h, ff2, g2, be2, (float*)d_out, nullptr);
}

// Round 7
// 423.949 us; speedup vs baseline: 1.6610x; 1.0061x over previous
//
#include <hip/hip_runtime.h>
#include <cmath>

// ---------------------------------------------------------------------------
// EncoderLayer: x -> MHA -> +res -> LN1 -> FFN(GELU) -> +res -> LN2
// B=2 L=2048 D=1024 H=16 dk=64 F=4096  (M = B*L = 4096 rows)
// bf16 MFMA 16x16x32, fp32 accumulate, fp32 LN/residual.
// GEMM: 128xTN dbuf global_load_lds pipeline, plain block mapping,
//       nt-innermost epilogue (write-combine friendly).
// Attention: S^T flash, 128 q/block (32 q/wave), dbuf K/V LDS staging,
//            perm-packed P, ballot-gated rescale.
// ---------------------------------------------------------------------------

typedef unsigned short u16;
typedef unsigned int u32;
typedef __attribute__((ext_vector_type(8))) __bf16 bf16x8;
typedef __attribute__((ext_vector_type(4))) float f32x4;

#define MFMA16(a, b, c) __builtin_amdgcn_mfma_f32_16x16x32_bf16(a, b, c, 0, 0, 0)

__device__ __forceinline__ u16 f2bf(float f) {
  u32 u = __builtin_bit_cast(u32, f);
  u += 0x7fffu + ((u >> 16) & 1u);   // round-to-nearest-even
  return (u16)(u >> 16);
}

// truncation-pack two fp32 -> bf16x2 in ONE v_perm_b32
__device__ __forceinline__ u32 packtrunc(float lo, float hi) {
#if __has_builtin(__builtin_amdgcn_perm)
  return __builtin_amdgcn_perm(__builtin_bit_cast(u32, hi),
                               __builtin_bit_cast(u32, lo), 0x07060302u);
#else
  return (__builtin_bit_cast(u32, lo) >> 16) |
         (__builtin_bit_cast(u32, hi) & 0xFFFF0000u);
#endif
}

__device__ __forceinline__ bf16x8 ld_frag(const u16* p) {
  return __builtin_bit_cast(bf16x8, *(const uint4*)p);
}

__device__ __forceinline__ float fexp2(float x) {
#if __has_builtin(__builtin_amdgcn_exp2f)
  return __builtin_amdgcn_exp2f(x);
#else
  return exp2f(x);
#endif
}

// async global->LDS, 16B per lane; LDS dest = wave-uniform base + lane*16
__device__ __forceinline__ void gload16(const u16* g, u16* l) {
  __builtin_amdgcn_global_load_lds(
      (const __attribute__((address_space(1))) void*)g,
      (__attribute__((address_space(3))) void*)l, 16, 0, 0);
}

// ---------------- fp32 -> bf16 elementwise convert (x) ----------------------
__global__ __launch_bounds__(256) void cvt_bf16_k(const float* __restrict__ src,
                                                  u16* __restrict__ dst) {
  int i = (blockIdx.x * 256 + threadIdx.x) * 4;
  float4 v = *(const float4*)(src + i);
  ushort4 o;
  o.x = f2bf(v.x); o.y = f2bf(v.y); o.z = f2bf(v.z); o.w = f2bf(v.w);
  *(ushort4*)(dst + i) = o;
}

// ---------------- fp32 [R][C] -> bf16 [C][R] transpose ----------------------
__global__ __launch_bounds__(256) void transpose_bf16_k(const float* __restrict__ src,
                                                        u16* __restrict__ dst,
                                                        int R, int C) {
  __shared__ float tile[32][33];
  int tx = threadIdx.x & 31, ty = threadIdx.x >> 5;  // 32 x 8
  int c0 = blockIdx.x * 32, r0 = blockIdx.y * 32;
#pragma unroll
  for (int i = 0; i < 4; i++)
    tile[ty + 8 * i][tx] = src[(long)(r0 + ty + 8 * i) * C + c0 + tx];
  __syncthreads();
#pragma unroll
  for (int i = 0; i < 4; i++)
    dst[(long)(c0 + ty + 8 * i) * R + r0 + tx] = f2bf(tile[tx][ty + 8 * i]);
}

// ---- 4x 1024x1024 fp32 -> bf16 transposes in one launch (z picks matrix) ---
__global__ __launch_bounds__(256) void transpose4_bf16_k(
    const float* __restrict__ Wq, const float* __restrict__ Wk,
    const float* __restrict__ Wv, const float* __restrict__ Wo,
    u16* __restrict__ wqkvT, u16* __restrict__ woT) {
  const int z = blockIdx.z;
  const float* src = (z == 0) ? Wq : (z == 1) ? Wk : (z == 2) ? Wv : Wo;
  u16* dst = (z < 3) ? (wqkvT + (size_t)z * 1024 * 1024) : woT;
  __shared__ float tile[32][33];
  int tx = threadIdx.x & 31, ty = threadIdx.x >> 5;
  int c0 = blockIdx.x * 32, r0 = blockIdx.y * 32;
#pragma unroll
  for (int i = 0; i < 4; i++)
    tile[ty + 8 * i][tx] = src[(long)(r0 + ty + 8 * i) * 1024 + c0 + tx];
  __syncthreads();
#pragma unroll
  for (int i = 0; i < 4; i++)
    dst[(long)(c0 + ty + 8 * i) * 1024 + r0 + tx] = f2bf(tile[tx][ty + 8 * i]);
}

// ---------------- GEMM: C[M][N] = A[M][K] * BT[N][K]^T ----------------------
// 128xTN block tile (TN = 128 or 64), BK=32, 4 waves in 2x2; wave tile
// 64 x TN/2. Double-buffered LDS, global_load_lds 16B, XOR-swizzled segs,
// ONE barrier per chunk; prefetch of chunk k+1 in flight across compute.
// Epilogues iterate nt INNERMOST so per-row segments merge in L2.
// MODE 0: QKV scatter epilogue; MODE 1: fp32+bias; MODE 2: bf16+bias+GELU.
template <int MODE, int TN>
__global__ __launch_bounds__(256) void gemm_k(
    const u16* __restrict__ A, const u16* __restrict__ BT, int M, int N, int K,
    const float* __restrict__ bias, float* __restrict__ outF, u16* __restrict__ outB,
    u16* __restrict__ qd, u16* __restrict__ kd, u16* __restrict__ vTd,
    const float* __restrict__ bq, const float* __restrict__ bk, const float* __restrict__ bv) {
  constexpr int NT = TN / 32;           // n-tiles per wave (4 or 2)
  __shared__ u16 As[2][128 * 32];
  __shared__ u16 Bs[2][TN * 32];
  const int tid = threadIdx.x;
  const int wave = tid >> 6, lane = tid & 63, quad = lane >> 4, l16 = lane & 15;
  const int wm = wave >> 1, wn = wave & 1;
  const int m0 = blockIdx.y * 128, n0 = blockIdx.x * TN;

  // staging: each issue = 16 rows x 1 seg(16B)/lane; seg XOR-swizzled by row
  const int srow = lane >> 2;                  // 0..15
  const int sxor = (lane & 3) ^ (srow & 3);    // swizzled source seg
  const u16* aS0 = A + (long)(m0 + wave * 32 + srow) * K + sxor * 8;
  const u16* aS1 = aS0 + 16 * K;
  const u16* bS0 = BT + (long)(n0 + (TN == 128 ? wave * 32 : wave * 16) + srow) * K + sxor * 8;
  const u16* bS1 = bS0 + 16 * K;  // used only when TN==128

  // fragment read offsets (u16 units): row*32 + (quad^(row&3))*8
  int aoff[4], boff[NT];
#pragma unroll
  for (int t = 0; t < 4; t++) {
    int ra = wm * 64 + t * 16 + l16;
    aoff[t] = ra * 32 + ((quad ^ (l16 & 3)) * 8);
  }
#pragma unroll
  for (int t = 0; t < NT; t++) {
    int rb = wn * (TN / 2) + t * 16 + l16;
    boff[t] = rb * 32 + ((quad ^ (l16 & 3)) * 8);
  }

  auto stage = [&](int buf, int k0) {
    gload16(aS0 + k0, &As[buf][(wave * 2 + 0) * 512]);
    gload16(aS1 + k0, &As[buf][(wave * 2 + 1) * 512]);
    if (TN == 128) {
      gload16(bS0 + k0, &Bs[buf][(wave * 2 + 0) * 512]);
      gload16(bS1 + k0, &Bs[buf][(wave * 2 + 1) * 512]);
    } else {
      gload16(bS0 + k0, &Bs[buf][wave * 512]);
    }
  };

  f32x4 acc[4][NT] = {};

  stage(0, 0);
#pragma unroll 1
  for (int k0 = 0; k0 < K; k0 += 32) {
    const int buf = (k0 >> 5) & 1;
    __syncthreads();                    // drains prefetch; prev reads done
    if (k0 + 32 < K) stage(buf ^ 1, k0 + 32);
    bf16x8 af[4], bfr[NT];
#pragma unroll
    for (int t = 0; t < 4; t++) af[t] = ld_frag(&As[buf][aoff[t]]);
#pragma unroll
    for (int t = 0; t < NT; t++) bfr[t] = ld_frag(&Bs[buf][boff[t]]);
#pragma unroll
    for (int mt = 0; mt < 4; mt++)
#pragma unroll
      for (int nt = 0; nt < NT; nt++)
        acc[mt][nt] = MFMA16(af[mt], bfr[nt], acc[mt][nt]);
  }

  if (MODE == 0) {
    const int nbase = n0 + wn * (TN / 2);
    const int mat = nbase >> 10;               // block-uniform (128 | 1024)
    const float* bp = (mat == 0) ? bq : ((mat == 1) ? bk : bv);
    float bb[NT];
    int hh0[NT], dd0[NT];
#pragma unroll
    for (int nt = 0; nt < NT; nt++) {
      int nn = (nbase + nt * 16 + l16) & 1023;
      bb[nt] = bp[nn];
      hh0[nt] = nn >> 6;
      dd0[nt] = nn & 63;
    }
    if (mat < 2) {
#pragma unroll
      for (int mt = 0; mt < 4; mt++) {
#pragma unroll
        for (int r = 0; r < 4; r++) {
          int mr = m0 + wm * 64 + mt * 16 + quad * 4 + r;
          int bI = mr >> 11, ll = mr & 2047;
#pragma unroll
          for (int nt = 0; nt < NT; nt++) {
            float v = acc[mt][nt][r] + bb[nt];
            long idx = ((long)((bI * 16 + hh0[nt]) * 2048 + ll)) * 64 + dd0[nt];
            if (mat == 0) {
              // fold 1/sqrt(dk)*log2(e) so attention uses exp2 directly
              qd[idx] = f2bf(v * 0.18033688011112043f);
            } else {
              kd[idx] = f2bf(v);
            }
          }
        }
      }
    } else {
#pragma unroll
      for (int nt = 0; nt < NT; nt++) {
#pragma unroll
        for (int mt = 0; mt < 4; mt++) {
#pragma unroll
          for (int r = 0; r < 4; r++) {
            int mr = m0 + wm * 64 + mt * 16 + quad * 4 + r;
            int bI = mr >> 11, ll = mr & 2047;
            float v = acc[mt][nt][r] + bb[nt];
            vTd[((long)((bI * 16 + hh0[nt]) * 64 + dd0[nt])) * 2048 + ll] = f2bf(v);
          }
        }
      }
    }
  } else if (MODE == 1) {
    float bb[NT];
#pragma unroll
    for (int nt = 0; nt < NT; nt++) bb[nt] = bias[n0 + wn * (TN / 2) + nt * 16 + l16];
#pragma unroll
    for (int mt = 0; mt < 4; mt++) {
#pragma unroll
      for (int r = 0; r < 4; r++) {
        int mr = m0 + wm * 64 + mt * 16 + quad * 4 + r;
        float* orow = outF + (long)mr * N + n0 + wn * (TN / 2) + l16;
#pragma unroll
        for (int nt = 0; nt < NT; nt++)
          orow[nt * 16] = acc[mt][nt][r] + bb[nt];
      }
    }
  } else {
    float bb[NT];
#pragma unroll
    for (int nt = 0; nt < NT; nt++) bb[nt] = bias[n0 + wn * (TN / 2) + nt * 16 + l16];
#pragma unroll
    for (int mt = 0; mt < 4; mt++) {
#pragma unroll
      for (int r = 0; r < 4; r++) {
        int mr = m0 + wm * 64 + mt * 16 + quad * 4 + r;
        u16* orow = outB + (long)mr * N + n0 + wn * (TN / 2) + l16;
#pragma unroll
        for (int nt = 0; nt < NT; nt++) {
          float v = acc[mt][nt][r] + bb[nt];
          v = 0.5f * v * (1.0f + erff(v * 0.70710678118654752f));  // exact GELU
          orow[nt * 16] = f2bf(v);
        }
      }
    }
  }
}

// ---------------- flash attention (S^T, LDS-staged K/V) ---------------------
// grid (L/128, B*H), 4 waves; wave owns 32 q rows (two 16-q sets); 64-key
// chunks. K tile [64 key][64 dk], V tile [64 dk][64 key], XOR-swizzled,
// double-buffered, global_load_lds staged. One barrier per chunk.
// q pre-scaled by 0.125*log2(e) -> p = exp2(s-m). P packed by truncation
// (single v_perm per pair). o-rescale gated by wave-uniform ballot.
__global__ __launch_bounds__(256) void attn_k(const u16* __restrict__ qd,
                                              const u16* __restrict__ kd,
                                              const u16* __restrict__ vTd,
                                              u16* __restrict__ ctx) {
  __shared__ u16 Ks[2][64 * 64];
  __shared__ u16 Vs[2][64 * 64];
  __shared__ __align__(16) u16 P[4][32][72];  // per-wave P^T bounce
  const int tid = threadIdx.x;
  const int wave = tid >> 6, lane = tid & 63, quad = lane >> 4, l16 = lane & 15;
  const int bh = blockIdx.y;
  const u16* Q = qd + (long)bh * 2048 * 64;
  const u16* Kp = kd + (long)bh * 2048 * 64;
  const u16* Vt = vTd + (long)bh * 64 * 2048;
  const int qbase = blockIdx.x * 128 + wave * 32;

  // Q as B operand: lane holds Q[q=l16][d = quad*8+j], two q-sets x two halves
  bf16x8 qf[2][2];
#pragma unroll
  for (int qs = 0; qs < 2; qs++) {
    qf[qs][0] = ld_frag(Q + (qbase + qs * 16 + l16) * 64 + quad * 8);
    qf[qs][1] = ld_frag(Q + (qbase + qs * 16 + l16) * 64 + 32 + quad * 8);
  }

  f32x4 o[2][4] = {};              // O^T[d = nt*16+quad*4+r][q = l16] per set
  float m[2] = {-1e30f, -1e30f}, l[2] = {0.f, 0.f};

  // staging: issue i covers 8 rows (128B each): r = wave*16 + i*8 + lane/8
  const int srow = lane >> 3;                // 0..7
  const int sx = (lane & 7) ^ srow;          // swizzled source seg (16B units)
  const int kr0 = wave * 16 + srow;
  const int kr1 = wave * 16 + 8 + srow;

  // fragment seg offsets (u16 units): (g ^ (l16&7))*8
  const int fs0 = ((0 * 4 + quad) ^ (l16 & 7)) * 8;
  const int fs1 = ((1 * 4 + quad) ^ (l16 & 7)) * 8;

  auto stage = [&](int buf, int j0) {
    gload16(Kp + (long)(j0 + kr0) * 64 + sx * 8, &Ks[buf][(wave * 2 + 0) * 512]);
    gload16(Kp + (long)(j0 + kr1) * 64 + sx * 8, &Ks[buf][(wave * 2 + 1) * 512]);
    gload16(Vt + (long)kr0 * 2048 + j0 + sx * 8, &Vs[buf][(wave * 2 + 0) * 512]);
    gload16(Vt + (long)kr1 * 2048 + j0 + sx * 8, &Vs[buf][(wave * 2 + 1) * 512]);
  };

  stage(0, 0);

#pragma unroll 1
  for (int j0 = 0; j0 < 2048; j0 += 64) {
    const int buf = (j0 >> 6) & 1;
    __syncthreads();                       // staged chunk visible; prev body done
    if (j0 + 64 < 2048) stage(buf ^ 1, j0 + 64);

    // ---- S^T = K Q^T over 64 keys, both q-sets (K frags shared) ----
    const u16* kb = &Ks[buf][0];
    f32x4 st[2][4];
#pragma unroll
    for (int f = 0; f < 4; f++) {
      bf16x8 k0 = ld_frag(kb + (f * 16 + l16) * 64 + fs0);
      bf16x8 k1 = ld_frag(kb + (f * 16 + l16) * 64 + fs1);
      f32x4 s0 = {}, s1 = {};
      s0 = MFMA16(k0, qf[0][0], s0); s0 = MFMA16(k1, qf[0][1], s0);
      s1 = MFMA16(k0, qf[1][0], s1); s1 = MFMA16(k1, qf[1][1], s1);
      st[0][f] = s0; st[1][f] = s1;
    }

    // ---- online softmax per q-set ----
#pragma unroll
    for (int qs = 0; qs < 2; qs++) {
      float mx = -1e30f;
#pragma unroll
      for (int f = 0; f < 4; f++)
        mx = fmaxf(mx, fmaxf(fmaxf(st[qs][f][0], st[qs][f][1]),
                             fmaxf(st[qs][f][2], st[qs][f][3])));
      mx = fmaxf(mx, __shfl_xor(mx, 16));
      mx = fmaxf(mx, __shfl_xor(mx, 32));
      if (__ballot(mx > m[qs])) {        // wave-uniform; exact (al==1 otherwise)
        float mn = fmaxf(m[qs], mx);
        float al = fexp2(m[qs] - mn);
        m[qs] = mn;
        l[qs] *= al;
#pragma unroll
        for (int nt = 0; nt < 4; nt++) {
          o[qs][nt][0] *= al; o[qs][nt][1] *= al;
          o[qs][nt][2] *= al; o[qs][nt][3] *= al;
        }
      }
      float sm = 0.f;
      u16* prow = &P[wave][qs * 16 + l16][0];
#pragma unroll
      for (int f = 0; f < 4; f++) {
        float p0 = fexp2(st[qs][f][0] - m[qs]);
        float p1 = fexp2(st[qs][f][1] - m[qs]);
        float p2 = fexp2(st[qs][f][2] - m[qs]);
        float p3 = fexp2(st[qs][f][3] - m[qs]);
        sm += (p0 + p1) + (p2 + p3);
        uint2 u;
        u.x = packtrunc(p0, p1);
        u.y = packtrunc(p2, p3);
        *(uint2*)(prow + f * 16 + quad * 4) = u;
      }
      sm += __shfl_xor(sm, 16);
      sm += __shfl_xor(sm, 32);
      l[qs] += sm;
    }
    // wave-internal write->read ordering (no inter-wave dep, no barrier)
    __asm__ volatile("s_waitcnt lgkmcnt(0)" ::: "memory");

    // ---- O^T += V^T P^T (V frags shared across q-sets) ----
    const u16* vb = &Vs[buf][0];
    bf16x8 vf[4][2];
#pragma unroll
    for (int nt = 0; nt < 4; nt++) {
      vf[nt][0] = ld_frag(vb + (nt * 16 + l16) * 64 + fs0);
      vf[nt][1] = ld_frag(vb + (nt * 16 + l16) * 64 + fs1);
    }
#pragma unroll
    for (int qs = 0; qs < 2; qs++) {
      const u16* prow = &P[wave][qs * 16 + l16][0];
#pragma unroll
      for (int kh = 0; kh < 2; kh++) {
        bf16x8 pf = ld_frag(prow + kh * 32 + quad * 8);
#pragma unroll
        for (int nt = 0; nt < 4; nt++)
          o[qs][nt] = MFMA16(vf[nt][kh], pf, o[qs][nt]);
      }
    }
  }

  // ---- epilogue: divide by l, write ctx[b][l][h*64+d] ----
  const int bI = bh >> 4, hh = bh & 15;
#pragma unroll
  for (int qs = 0; qs < 2; qs++) {
    const float rl = 1.0f / l[qs];
    const long row = (long)(bI * 2048 + qbase + qs * 16 + l16);
#pragma unroll
    for (int nt = 0; nt < 4; nt++) {
      ushort4 w;
      w.x = f2bf(o[qs][nt][0] * rl);
      w.y = f2bf(o[qs][nt][1] * rl);
      w.z = f2bf(o[qs][nt][2] * rl);
      w.w = f2bf(o[qs][nt][3] * rl);
      *(ushort4*)(ctx + row * 1024 + hh * 64 + nt * 16 + quad * 4) = w;
    }
  }
}

// ---------------- residual + LayerNorm -------------------------------------
__global__ __launch_bounds__(256) void ln_k(const float* __restrict__ a,
                                            const float* __restrict__ b,
                                            const float* __restrict__ g,
                                            const float* __restrict__ be,
                                            float* __restrict__ outF,
                                            u16* __restrict__ outB) {
  const int row = blockIdx.x, tid = threadIdx.x;
  const float* pa = a + (long)row * 1024;
  const float* pb = b + (long)row * 1024;
  float v[4], s = 0.f, sq = 0.f;
#pragma unroll
  for (int i = 0; i < 4; i++) {
    int c = i * 256 + tid;
    v[i] = pa[c] + pb[c];
    s += v[i];
    sq += v[i] * v[i];
  }
#pragma unroll
  for (int off = 1; off < 64; off <<= 1) {
    s += __shfl_xor(s, off);
    sq += __shfl_xor(sq, off);
  }
  __shared__ float red[10];
  int wave = tid >> 6, lane = tid & 63;
  if (lane == 0) { red[wave * 2] = s; red[wave * 2 + 1] = sq; }
  __syncthreads();
  if (tid == 0) {
    float S = red[0] + red[2] + red[4] + red[6];
    float Q = red[1] + red[3] + red[5] + red[7];
    float mu = S * (1.0f / 1024.0f);
    float var = Q * (1.0f / 1024.0f) - mu * mu;
    red[8] = mu;
    red[9] = rsqrtf(var + 1e-5f);
  }
  __syncthreads();
  float mu = red[8], rstd = red[9];
#pragma unroll
  for (int i = 0; i < 4; i++) {
    int c = i * 256 + tid;
    float o = (v[i] - mu) * rstd * g[c] + be[c];
    outF[(long)row * 1024 + c] = o;
    if (outB) outB[(long)row * 1024 + c] = f2bf(o);
  }
}

// ---------------------------------------------------------------------------
extern "C" void kernel_launch(void* const* d_in, const int* in_sizes, int n_in,
                              void* d_out, int out_size, void* d_ws, size_t ws_size,
                              hipStream_t stream) {
  const float* x  = (const float*)d_in[0];
  const float* Wq = (const float*)d_in[1];  const float* bq = (const float*)d_in[2];
  const float* Wk = (const float*)d_in[3];  const float* bk = (const float*)d_in[4];
  const float* Wv = (const float*)d_in[5];  const float* bv = (const float*)d_in[6];
  const float* Wo = (const float*)d_in[7];  const float* bo = (const float*)d_in[8];
  const float* W1 = (const float*)d_in[9];  const float* b1 = (const float*)d_in[10];
  const float* W2 = (const float*)d_in[11]; const float* b2 = (const float*)d_in[12];
  const float* g1 = (const float*)d_in[13]; const float* be1 = (const float*)d_in[14];
  const float* g2 = (const float*)d_in[15]; const float* be2 = (const float*)d_in[16];

  char* ws = (char*)d_ws;
  size_t off = 0;
  auto alloc = [&](size_t bytes) {
    size_t o = off;
    off += (bytes + 255) & ~(size_t)255;
    return o;
  };
  u16*   xb     = (u16*)(ws + alloc(4096UL * 1024 * 2));
  u16*   wqkvT  = (u16*)(ws + alloc(3072UL * 1024 * 2));
  u16*   woT    = (u16*)(ws + alloc(1024UL * 1024 * 2));
  u16*   w1T    = (u16*)(ws + alloc(4096UL * 1024 * 2));
  u16*   w2T    = (u16*)(ws + alloc(1024UL * 4096 * 2));
  u16*   qb     = (u16*)(ws + alloc(32UL * 2048 * 64 * 2));
  u16*   kb     = (u16*)(ws + alloc(32UL * 2048 * 64 * 2));
  u16*   vTb    = (u16*)(ws + alloc(32UL * 64 * 2048 * 2));
  u16*   ctx    = (u16*)(ws + alloc(4096UL * 1024 * 2));
  float* attnO  = (float*)(ws + alloc(4096UL * 1024 * 4));
  float* h      = (float*)(ws + alloc(4096UL * 1024 * 4));
  u16*   hb     = (u16*)(ws + alloc(4096UL * 1024 * 2));
  u16*   ff1    = (u16*)(ws + alloc(4096UL * 4096 * 2));
  float* ff2    = (float*)(ws + alloc(4096UL * 1024 * 4));
  if (off > ws_size) return;  // workspace too small: bail (bench will flag)

  // 1) bf16 conversions / weight transposes
  cvt_bf16_k<<<4096, 256, 0, stream>>>(x, xb);
  transpose4_bf16_k<<<dim3(32, 32, 4), 256, 0, stream>>>(Wq, Wk, Wv, Wo, wqkvT, woT);
  transpose_bf16_k<<<dim3(128, 32), 256, 0, stream>>>(W1, w1T, 1024, 4096);
  transpose_bf16_k<<<dim3(32, 128), 256, 0, stream>>>(W2, w2T, 4096, 1024);

  // 2) QKV projection (N=3072 fused), scatter epilogue
  gemm_k<0, 128><<<dim3(24, 32), 256, 0, stream>>>(xb, wqkvT, 4096, 3072, 1024,
                                                   nullptr, nullptr, nullptr,
                                                   qb, kb, vTb, bq, bk, bv);
  // 3) attention (128 q per block)
  attn_k<<<dim3(16, 32), 256, 0, stream>>>(qb, kb, vTb, ctx);
  // 4) output projection (N=1024: TN=64 -> 512 blocks)
  gemm_k<1, 64><<<dim3(16, 32), 256, 0, stream>>>(ctx, woT, 4096, 1024, 1024,
                                                  bo, attnO, nullptr,
                                                  nullptr, nullptr, nullptr, nullptr, nullptr, nullptr);
  // 5) residual + LN1 (fp32 h + bf16 hb)
  ln_k<<<4096, 256, 0, stream>>>(x, attnO, g1, be1, h, hb);
  // 6) FFN up + GELU
  gemm_k<2, 128><<<dim3(32, 32), 256, 0, stream>>>(hb, w1T, 4096, 4096, 1024,
                                                   b1, nullptr, ff1,
                                                   nullptr, nullptr, nullptr, nullptr, nullptr, nullptr);
  // 7) FFN down (N=1024: TN=64 -> 512 blocks)
  gemm_k<1, 64><<<dim3(16, 32), 256, 0, stream>>>(ff1, w2T, 4096, 1024, 4096,
                                                  b2, ff2, nullptr,
                                                  nullptr, nullptr, nullptr, nullptr, nullptr, nullptr);
  // 8) residual + LN2 -> out
  ln_k<<<4096, 256, 0, stream>>>(h, ff2, g2, be2, (float*)d_out, nullptr);
}